// Round 10
// baseline (464.172 us; speedup 1.0000x reference)
//
#include <hip/hip_runtime.h>

typedef float f32x4 __attribute__((ext_vector_type(4)));
typedef short bf16x8 __attribute__((ext_vector_type(8)));
typedef _Float16 f16x8 __attribute__((ext_vector_type(8)));
typedef __fp16 fp16x2 __attribute__((ext_vector_type(2)));

constexpr int kB  = 4;
constexpr int kN  = 4096;
constexpr int kC  = 512;
constexpr int kH  = 8;
constexpr int kHD = 64;
constexpr int kM  = 1024;
constexpr int kC3 = 1536;

// pack 2 floats -> 2 fp16 in one dword (v_cvt_pkrtz_f16_f32, 1 inst)
__device__ inline unsigned pkh(float a, float b) {
    union { fp16x2 h; unsigned u; } u;
    u.h = __builtin_amdgcn_cvt_pkrtz(a, b);
    return u.u;
}

// li += ph.lo + ph.hi via v_dot2_f32_f16 (ones = 0x3C003C00)
__device__ inline float fdot2a(unsigned ph, unsigned ones, float acc) {
    asm("v_dot2_f32_f16 %0, %1, %2, %0" : "+v"(acc) : "v"(ph), "v"(ones));
    return acc;
}

// permlane swaps: exchange quad-rows between two regs (gfx950).
__device__ inline void swap32p(unsigned &a, unsigned &b) {
#if __has_builtin(__builtin_amdgcn_permlane32_swap)
    auto r = __builtin_amdgcn_permlane32_swap(a, b, false, false);
    a = r[0]; b = r[1];
#else
    asm volatile("v_permlane32_swap_b32 %0, %1" : "+v"(a), "+v"(b));
#endif
}
__device__ inline void swap16p(unsigned &a, unsigned &b) {
#if __has_builtin(__builtin_amdgcn_permlane16_swap)
    auto r = __builtin_amdgcn_permlane16_swap(a, b, false, false);
    a = r[0]; b = r[1];
#else
    asm volatile("v_permlane16_swap_b32 %0, %1" : "+v"(a), "+v"(b));
#endif
}

// async global->LDS, 16B per lane. LDS dest = uniform base + lane*16.
__device__ inline void gl_lds16(const _Float16* g, _Float16* l) {
    __builtin_amdgcn_global_load_lds(
        (const __attribute__((address_space(1))) unsigned int*)(const void*)g,
        (__attribute__((address_space(3))) unsigned int*)(void*)l, 16, 0, 0);
}

// ---------------------------------------------------------------------------
// cvt_f16: fp32 -> fp16 flat. n4 = count/4.
// ---------------------------------------------------------------------------
__global__ __launch_bounds__(256) void cvt_f16(
    const float* __restrict__ X, _Float16* __restrict__ Y, int n4)
{
    int i = blockIdx.x * 256 + threadIdx.x;
    if (i >= n4) return;
    float4 v = ((const float4*)X)[i];
    union { _Float16 h[4]; short4 s; } u;
    u.h[0] = (_Float16)v.x; u.h[1] = (_Float16)v.y;
    u.h[2] = (_Float16)v.z; u.h[3] = (_Float16)v.w;
    ((short4*)Y)[i] = u.s;
}

// ---------------------------------------------------------------------------
// wcvtT16: W [K][N] fp32 -> T [N][K] fp16 (transposed)
// ---------------------------------------------------------------------------
__global__ __launch_bounds__(256) void wcvtT16(
    const float* __restrict__ W, int K, int N, _Float16* __restrict__ T16)
{
    __shared__ float T[64][65];
    const int n0 = blockIdx.x * 64, k0 = blockIdx.y * 64;
    const int t = threadIdx.x;
#pragma unroll
    for (int i = 0; i < 4; i++) {
        int c = t + i * 256;
        int row = c >> 4, col4 = (c & 15) * 4;
        *(float4*)&T[row][col4] = *(const float4*)&W[(size_t)(k0 + row) * N + n0 + col4];
    }
    __syncthreads();
#pragma unroll
    for (int i = 0; i < 4; i++) {
        int c = t + i * 256;
        int nrow = c >> 4, kc4 = (c & 15) * 4;
        union { _Float16 h[4]; short4 s; } u;
        u.h[0] = (_Float16)T[kc4 + 0][nrow];
        u.h[1] = (_Float16)T[kc4 + 1][nrow];
        u.h[2] = (_Float16)T[kc4 + 2][nrow];
        u.h[3] = (_Float16)T[kc4 + 3][nrow];
        *(short4*)&T16[(size_t)(n0 + nrow) * K + k0 + kc4] = u.s;
    }
}

// ---------------------------------------------------------------------------
// transpose_hd: [bh][nTok][64] -> [bh][64][nTok], 2 arrays (bit-agnostic 16b).
// ---------------------------------------------------------------------------
__global__ __launch_bounds__(256) void transpose_hd(
    const short* __restrict__ s0, const short* __restrict__ s1,
    short* __restrict__ d0, short* __restrict__ d1, int nTok)
{
    __shared__ short T[64][72];
    const short* src = blockIdx.z == 0 ? s0 : s1;
    short*       dst = blockIdx.z == 0 ? d0 : d1;
    const int n0 = blockIdx.x * 64, bh = blockIdx.y;
    const int t = threadIdx.x;
#pragma unroll
    for (int i = 0; i < 2; i++) {
        int c = t + i * 256;
        int row = c >> 3, j = (c & 7) * 8;
        *(bf16x8*)&T[row][j] = *(const bf16x8*)&src[((size_t)bh * nTok + n0 + row) * 64 + j];
    }
    __syncthreads();
#pragma unroll
    for (int i = 0; i < 2; i++) {
        int c = t + i * 256;
        int drow = c >> 3, j = (c & 7) * 8;
        bf16x8 v;
#pragma unroll
        for (int q = 0; q < 8; q++) v[q] = T[j + q][drow];
        *(bf16x8*)&dst[((size_t)bh * 64 + drow) * nTok + n0 + j] = v;
    }
}

// ---------------------------------------------------------------------------
// gemm_f16: C[Md,Nd] = A[Md,Kd] @ B^T[Nd,Kd], fp16 in, fp32 accumulate.
// mode 0: Cf[row][col] = acc + bias (fp32). mode 1: qkv scatter to fp16,
// with q pre-scaled by qscale. 128x128 tile, BK=32, 4 waves.
// Staging via async global_load_lds width=16 (m97 structure).
// ---------------------------------------------------------------------------
__global__ __launch_bounds__(256) void gemm_f16(
    const _Float16* __restrict__ A, const _Float16* __restrict__ B,
    int Md, int Nd, int Kd, int mode, float qscale,
    const float* __restrict__ bias, float* __restrict__ Cf,
    _Float16* __restrict__ q, _Float16* __restrict__ k, _Float16* __restrict__ v)
{
    __shared__ _Float16 Ash[128][32], Bsh[128][32];
    const int t = threadIdx.x, lane = t & 63, L = lane & 15, quad = lane >> 4;
    const int wave = t >> 6, wm = wave >> 1, wn = wave & 1;
    const int bm = blockIdx.y * 128, bn = blockIdx.x * 128;
    const int r16 = lane >> 2, c16 = lane & 3;   // staging: row-in-chunk, col16

    f32x4 acc[4][4];
#pragma unroll
    for (int i = 0; i < 4; i++)
#pragma unroll
        for (int j = 0; j < 4; j++) acc[i][j] = (f32x4){0.f, 0.f, 0.f, 0.f};

    for (int k0 = 0; k0 < Kd; k0 += 32) {
#pragma unroll
        for (int i = 0; i < 2; i++) {
            int chunk = wave * 2 + i;          // 8 chunks of 16 rows
            int row = chunk * 16 + r16;
            gl_lds16(&A[(size_t)(bm + row) * Kd + k0 + c16 * 8], &Ash[chunk * 16][0]);
            gl_lds16(&B[(size_t)(bn + row) * Kd + k0 + c16 * 8], &Bsh[chunk * 16][0]);
        }
        __syncthreads();
        f16x8 af[4];
#pragma unroll
        for (int mi = 0; mi < 4; mi++)
            af[mi] = *(const f16x8*)&Ash[wm * 64 + mi * 16 + L][quad * 8];
#pragma unroll
        for (int ni = 0; ni < 4; ni++) {
            f16x8 bf = *(const f16x8*)&Bsh[wn * 64 + ni * 16 + L][quad * 8];
#pragma unroll
            for (int mi = 0; mi < 4; mi++)
                acc[mi][ni] = __builtin_amdgcn_mfma_f32_16x16x32_f16(af[mi], bf, acc[mi][ni], 0, 0, 0);
        }
        __syncthreads();
    }

    if (mode == 0) {
#pragma unroll
        for (int ni = 0; ni < 4; ni++) {
            int col = bn + wn * 64 + ni * 16 + L;
            float bb = bias ? bias[col] : 0.f;
#pragma unroll
            for (int mi = 0; mi < 4; mi++)
#pragma unroll
                for (int r = 0; r < 4; r++) {
                    int row = bm + wm * 64 + mi * 16 + quad * 4 + r;
                    Cf[(size_t)row * Nd + col] = acc[mi][ni][r] + bb;
                }
        }
    } else {
#pragma unroll
        for (int ni = 0; ni < 4; ni++) {
            int col = bn + wn * 64 + ni * 16 + L;
            int s = col >> 9, h = (col >> 6) & 7, d = col & 63;
            _Float16* dst = s == 0 ? q : s == 1 ? k : v;
            float sc = (s == 0) ? qscale : 1.0f;
#pragma unroll
            for (int mi = 0; mi < 4; mi++)
#pragma unroll
                for (int r = 0; r < 4; r++) {
                    int row = bm + wm * 64 + mi * 16 + quad * 4 + r;
                    int b = row >> 12, n = row & 4095;
                    size_t idx = (((size_t)b * 8 + h) * 4096 + n) * 64 + d;
                    dst[idx] = (_Float16)(acc[mi][ni][r] * sc);
                }
        }
    }
}

// ---------------------------------------------------------------------------
// sr_fused: depthwise 2x2/s2 conv + LayerNorm + linear -> xsr fp16.
// Output pre-scaled by log2e (softmax scale fold, f32-side, rounding-neutral).
// ---------------------------------------------------------------------------
__global__ __launch_bounds__(256) void sr_fused(
    const float* __restrict__ x, const float* __restrict__ wconv,
    const float* __restrict__ bconv, const float* __restrict__ gamma,
    const float* __restrict__ beta, const float* __restrict__ wlin,
    const float* __restrict__ blin, _Float16* __restrict__ xsr)
{
    __shared__ float nbuf[512];
    __shared__ float red[8];
    __shared__ float stats[2];
    __shared__ float pbuf[4][64];

    const int m = blockIdx.x, b = blockIdx.y;
    const int oy = m >> 5, ox = m & 31;
    const int t = threadIdx.x;
    const float* xb = x + (size_t)b * kN * kC;

    float vals[2], s = 0.f, sq = 0.f;
#pragma unroll
    for (int i = 0; i < 2; i++) {
        int c = t + i * 256;
        float acc = bconv[c];
#pragma unroll
        for (int dy = 0; dy < 2; dy++)
#pragma unroll
            for (int dx = 0; dx < 2; dx++) {
                int n = (oy * 2 + dy) * 64 + (ox * 2 + dx);
                acc += xb[(size_t)n * kC + c] * wconv[c * 4 + dy * 2 + dx];
            }
        vals[i] = acc;
        s += acc; sq += acc * acc;
    }
#pragma unroll
    for (int off = 32; off > 0; off >>= 1) {
        s  += __shfl_down(s,  off);
        sq += __shfl_down(sq, off);
    }
    if ((t & 63) == 0) { red[t >> 6] = s; red[4 + (t >> 6)] = sq; }
    __syncthreads();
    if (t == 0) {
        float ts = red[0] + red[1] + red[2] + red[3];
        float tq = red[4] + red[5] + red[6] + red[7];
        float mean = ts * (1.f / 512.f);
        float var  = tq * (1.f / 512.f) - mean * mean;
        stats[0] = mean;
        stats[1] = rsqrtf(var + 1e-5f);
    }
    __syncthreads();
    const float mean = stats[0], rstd = stats[1];
#pragma unroll
    for (int i = 0; i < 2; i++) {
        int c = t + i * 256;
        nbuf[c] = (vals[i] - mean) * rstd * gamma[c] + beta[c];
    }
    __syncthreads();
    const int d = t & 63, part = t >> 6;
    float p = 0.f;
    for (int c = part * 128; c < (part + 1) * 128; c++)
        p += nbuf[c] * wlin[c * 64 + d];
    pbuf[part][d] = p;
    __syncthreads();
    if (t < 64) {
        float o = pbuf[0][t] + pbuf[1][t] + pbuf[2][t] + pbuf[3][t] + blin[t];
        xsr[((size_t)b * kM + m) * kHD + t] = (_Float16)(o * 1.44269504089f);
    }
}

// ---------------------------------------------------------------------------
// MFMA flash attention, fp16, transposed-S, in-register P^T via permlane
// swaps, XCD-aware work remap, BM=256 / 8 waves / 512 threads.
// HYBRID STAGING: K double-buffered in LDS (reads feed MFMA immediately ->
// needs the pipelined LDS path); V read DIRECTLY from global as per-lane
// fragments ISSUED AT TILE START and consumed only after QK+softmax+permlane
// (~500+ cyc later) -> L2 latency fully hidden (T14). Halves the per-tile
// LDS burst (18 -> 9 b128 ops/wave) that the barrier-synchronized rounds
// were queueing on, and removes the VTs buffer + its bank conflicts.
// V slice is L2-resident via the h-pin; the 8KB V-tile is shared by the
// block's 8 waves through L1.
// LDS: 2 x 9216 = 18,432 B.
// ---------------------------------------------------------------------------
__global__ __launch_bounds__(512, 4) void flash_mfma(
    const _Float16* __restrict__ Q, long q_bs, long q_hs,
    const _Float16* __restrict__ K0, const _Float16* __restrict__ K1,
    long k_bs, long k_hs,
    const _Float16* __restrict__ VT0, const _Float16* __restrict__ VT1,
    long v_bs, long v_hs, int v_rs,
    _Float16* __restrict__ O,
    long o_bs, long o_hs, long o_rs, int o_cs,
    int nKtot, int nChunks, int kvMerge,
    _Float16* __restrict__ Opart, float* __restrict__ MLpart)
{
    __shared__ _Float16 Ks[2][64][72];
    const int t = threadIdx.x, lane = t & 63, L = lane & 15, quad = lane >> 4;
    const int wave = t >> 6;                       // 0..7
    // XCD-aware remap. Bijective over (x,y); requires gridDim.y==8, gx%8==0.
    const int h = blockIdx.x & 7;
    const int rest = (blockIdx.x >> 3) + (gridDim.x >> 3) * blockIdx.y;
    int b, which, nB;
    if (kvMerge) { b = blockIdx.z >> 1; which = blockIdx.z & 1; nB = gridDim.z >> 1; }
    else         { b = blockIdx.z;      which = 0;              nB = gridDim.z; }
    const int nMblk = gridDim.x / nChunks;
    const int mblk = rest / nChunks, chunk = rest % nChunks;
    const int m0 = mblk * 256;
    const int nkc = nKtot / nChunks, nbeg = chunk * nkc, nend = nbeg + nkc;
    const unsigned kOnes = 0x3C003C00u;             // fp16x2 (1.0, 1.0)

    const _Float16* K_ = (which ? K1 : K0) + (size_t)b * k_bs + (size_t)h * k_hs;
    const _Float16* V_ = (which ? VT1 : VT0) + (size_t)b * v_bs + (size_t)h * v_hs;
    // per-lane V fragment base: row L (+dch*16), col quad*8 (+n0+h2*32)
    const _Float16* Vlane = V_ + (size_t)L * v_rs + quad * 8;

    // Q as B-fragments (each wave owns rows m0 + wave*32 + s*16 + L)
    f16x8 qf[2][2];
#pragma unroll
    for (int s = 0; s < 2; s++) {
        const size_t qrow = (size_t)b * q_bs + (size_t)h * q_hs
                          + (size_t)(m0 + wave * 32 + s * 16 + L) * 64;
        qf[s][0] = *(const f16x8*)&Q[qrow + quad * 8];
        qf[s][1] = *(const f16x8*)&Q[qrow + 32 + quad * 8];
    }

    f32x4 Oacc[2][4];
#pragma unroll
    for (int s = 0; s < 2; s++)
#pragma unroll
        for (int i = 0; i < 4; i++) Oacc[s][i] = (f32x4){0.f, 0.f, 0.f, 0.f};
    float li[2] = {0.f, 0.f};   // per-lane partial; reduced across quads at end

    // K staging geometry: 512 threads cover [64][64] once: row t>>3, col (t&7)*8
    const int sr = t >> 3, sj = (t & 7) * 8;

    // prologue: stage K tile nbeg into buffer 0
    {
        f16x8 a0 = *(const f16x8*)&K_[(size_t)(nbeg + sr) * 64 + sj];
        *(f16x8*)&Ks[0][sr][sj] = a0;
    }
    __syncthreads();

    int cur = 0;
    for (int n0 = nbeg; n0 < nend; n0 += 64) {
        // V fragments for THIS tile: issued now, consumed after QK+softmax
        // (~500 cyc later) -> latency hidden under compute.
        f16x8 vf[2][4];
#pragma unroll
        for (int h2 = 0; h2 < 2; h2++)
#pragma unroll
            for (int dch = 0; dch < 4; dch++)
                vf[h2][dch] = *(const f16x8*)&Vlane[(size_t)(dch * 16) * v_rs
                                                    + n0 + h2 * 32];

        // next K tile's global load (in flight across the compute phase)
        int nn = (n0 + 64 < nend) ? n0 + 64 : nbeg;
        f16x8 kp0 = *(const f16x8*)&K_[(size_t)(nn + sr) * 64 + sj];

        // QK^T (S^T layout) fused with softmax exp + fp16 pack.
        unsigned d0[2][4], d1[2][4];
#pragma unroll
        for (int c = 0; c < 4; c++) {
            f16x8 k0 = *(const f16x8*)&Ks[cur][c * 16 + L][quad * 8];
            f16x8 k1 = *(const f16x8*)&Ks[cur][c * 16 + L][32 + quad * 8];
#pragma unroll
            for (int s = 0; s < 2; s++) {
                f32x4 a = (f32x4){0.f, 0.f, 0.f, 0.f};
                a = __builtin_amdgcn_mfma_f32_16x16x32_f16(k0, qf[s][0], a, 0, 0, 0);
                a = __builtin_amdgcn_mfma_f32_16x16x32_f16(k1, qf[s][1], a, 0, 0, 0);
                float p0 = exp2f(a[0]);
                float p1 = exp2f(a[1]);
                float p2 = exp2f(a[2]);
                float p3 = exp2f(a[3]);
                d0[s][c] = pkh(p0, p1);
                d1[s][c] = pkh(p2, p3);
                li[s] = fdot2a(d0[s][c], kOnes, li[s]);
                li[s] = fdot2a(d1[s][c], kOnes, li[s]);
            }
        }

        // in-register P^T: build B-fragments pt[s][h2]
        f16x8 pt[2][2];
#pragma unroll
        for (int s = 0; s < 2; s++)
#pragma unroll
            for (int h2 = 0; h2 < 2; h2++) {
                unsigned a0 = d0[s][h2 * 2], b0 = d0[s][h2 * 2 + 1];
                swap32p(a0, b0); swap16p(a0, b0);
                unsigned a1 = d1[s][h2 * 2], b1 = d1[s][h2 * 2 + 1];
                swap32p(a1, b1); swap16p(a1, b1);
                union { unsigned u[4]; f16x8 v; } U;
                U.u[0] = a0; U.u[1] = a1; U.u[2] = b0; U.u[3] = b1;
                pt[s][h2] = U.v;
            }

#pragma unroll
        for (int h2 = 0; h2 < 2; h2++) {
#pragma unroll
            for (int dch = 0; dch < 4; dch++) {
                Oacc[0][dch] = __builtin_amdgcn_mfma_f32_16x16x32_f16(vf[h2][dch], pt[0][h2], Oacc[0][dch], 0, 0, 0);
                Oacc[1][dch] = __builtin_amdgcn_mfma_f32_16x16x32_f16(vf[h2][dch], pt[1][h2], Oacc[1][dch], 0, 0, 0);
            }
        }

        // stage next K tile into the alternate buffer (WAR-safe)
        *(f16x8*)&Ks[cur ^ 1][sr][sj] = kp0;
        __syncthreads();
        cur ^= 1;
    }

    // reduce li across quads (each lane held its quad's partial)
    float lt[2];
#pragma unroll
    for (int s = 0; s < 2; s++) {
        float v = li[s];
        v += __shfl_xor(v, 16);
        v += __shfl_xor(v, 32);
        lt[s] = v;
    }

    if (Opart) {
        int pid = (((which * nB + b) * gridDim.y + h) * nMblk + mblk) * nChunks + chunk;
        _Float16* Ob = Opart + (size_t)pid * (256 * 64);
        float* Mb = MLpart + (size_t)pid * 256;
#pragma unroll
        for (int s = 0; s < 2; s++) {
            int mloc = wave * 32 + s * 16 + L;
            float inv = 1.f / lt[s];
#pragma unroll
            for (int dch = 0; dch < 4; dch++) {
                union { _Float16 h[4]; uint2 u; } U;
#pragma unroll
                for (int r = 0; r < 4; r++)
                    U.h[r] = (_Float16)(Oacc[s][dch][r] * inv);
                *(uint2*)&Ob[mloc * 64 + dch * 16 + quad * 4] = U.u;
            }
            if (quad == 0) Mb[mloc] = lt[s];
        }
    } else {
#pragma unroll
        for (int s = 0; s < 2; s++) {
            float inv = 1.f / lt[s];
            size_t base = (size_t)b * o_bs + (size_t)h * o_hs
                        + (size_t)(m0 + wave * 32 + s * 16 + L) * o_rs;
#pragma unroll
            for (int dch = 0; dch < 4; dch++)
#pragma unroll
                for (int r = 0; r < 4; r++) {
                    int d = dch * 16 + quad * 4 + r;
                    O[base + (size_t)d * o_cs] = (_Float16)(Oacc[s][dch][r] * inv);
                }
        }
    }
}

// ---------------------------------------------------------------------------
// flash_combine: merge nChunks normalized fp16 partials, weighted by l.
// grid (M/4, H, B), 256 threads = 4 queries x 64 d. BM=256 partial layout:
// per-pid Opart 256x64 fp16, MLpart 256 floats.
// ---------------------------------------------------------------------------
__global__ __launch_bounds__(256) void flash_combine(
    const _Float16* __restrict__ Opart, const float* __restrict__ MLpart,
    int nMblk, int nChunks,
    _Float16* __restrict__ O, long o_bs, long o_hs, long o_rs, int o_cs)
{
    const int t = threadIdx.x;
    const int b = blockIdx.z, h = blockIdx.y;
    const int qm = blockIdx.x * 4 + (t >> 6), d = t & 63;
    const int mblk = qm >> 8, qloc = qm & 255;
    const int pb = ((b * gridDim.y + h) * nMblk + mblk) * nChunks;
    float num = 0.f, den = 0.f;
    for (int c = 0; c < nChunks; c++) {
        float lc = MLpart[(size_t)(pb + c) * 256 + qloc];
        num += lc * (float)Opart[(size_t)(pb + c) * 16384 + qloc * 64 + d];
        den += lc;
    }
    size_t addr = (size_t)b * o_bs + (size_t)h * o_hs + (size_t)qm * o_rs + (size_t)d * o_cs;
    O[addr] = (_Float16)(num / den);
}

// ---------------------------------------------------------------------------
extern "C" void kernel_launch(void* const* d_in, const int* in_sizes, int n_in,
                              void* d_out, int out_size, void* d_ws, size_t ws_size,
                              hipStream_t stream)
{
    const float* x      = (const float*)d_in[0];
    const float* w_qkv  = (const float*)d_in[1];
    const float* w_proj = (const float*)d_in[2];
    const float* b_proj = (const float*)d_in[3];
    const float* w_conv = (const float*)d_in[4];
    const float* b_conv = (const float*)d_in[5];
    const float* g_ln   = (const float*)d_in[6];
    const float* b_ln   = (const float*)d_in[7];
    const float* w_lin  = (const float*)d_in[8];
    const float* b_lin  = (const float*)d_in[9];
    float* out = (float*)d_out;
    (void)in_sizes; (void)n_in; (void)out_size; (void)ws_size;

    short* p = (short*)d_ws;
    size_t off = 0;
    auto alloc = [&](size_t n) { short* r = p + off; off += n; return r; };

    const size_t TN = (size_t)kB * kH * kN * kHD;   // 8.39M elems
    const size_t TM = (size_t)kB * kH * kM * kHD;   // 2.10M elems

    // region0: xf16, later ao (both fp16, lifetimes disjoint)
    _Float16* xf16 = (_Float16*)alloc((size_t)kB * kN * kC);
    _Float16* ao   = xf16;

    _Float16* wq16 = (_Float16*)alloc((size_t)kC3 * kC);
    _Float16* wp16 = (_Float16*)alloc((size_t)kC * kC);
    _Float16* qh  = (_Float16*)alloc(TN);
    _Float16* kh  = (_Float16*)alloc(TN);
    _Float16* vh  = (_Float16*)alloc(TN);
    _Float16* kT  = (_Float16*)alloc(TN);
    _Float16* vT  = (_Float16*)alloc(TN);
    _Float16* xsr = (_Float16*)alloc((size_t)kB * kM * kHD);
    _Float16* kc  = (_Float16*)alloc(TM);
    _Float16* vc  = (_Float16*)alloc(TM);   // [b,h,m,d] coalesced combine out
    _Float16* vcT = (_Float16*)alloc(TM);   // [b,h,d,m] for PV fragments
    float*    MLpart = (float*)alloc((size_t)2048 * 128 * 2);
    _Float16* Opart  = (_Float16*)alloc((size_t)2048 * 8192);  // fp16 partials

    const int NCH = 4;   // compress key-chunks

    // 1. x -> fp16
    cvt_f16<<<(kB * kN * kC / 4 + 255) / 256, 256, 0, stream>>>(
        x, xf16, kB * kN * kC / 4);

    // 2. weights -> fp16 transposed
    wcvtT16<<<dim3(kC3 / 64, kC / 64), 256, 0, stream>>>(w_qkv, kC, kC3, wq16);
    wcvtT16<<<dim3(kC / 64, kC / 64), 256, 0, stream>>>(w_proj, kC, kC, wp16);

    // 3. qkv GEMM (fp16) -> q,k,v fp16 [b,h,n,d]; q pre-scaled by
    //    attn_scale*log2e = 0.125*1.4427
    gemm_f16<<<dim3(kC3 / 128, kB * kN / 128), 256, 0, stream>>>(
        xf16, wq16, kB * kN, kC3, kC, 1, 0.18033688f, nullptr, nullptr,
        qh, kh, vh);

    // 4. k,v -> kT,vT ([b,h,d,n])
    transpose_hd<<<dim3(kN / 64, kB * kH, 2), 256, 0, stream>>>(
        (const short*)kh, (const short*)vh, (short*)kT, (short*)vT, kN);

    // 5. SR branch -> xsr fp16 (pre-scaled by log2e)
    sr_fused<<<dim3(kM, kB), 256, 0, stream>>>(
        x, w_conv, b_conv, g_ln, b_ln, w_lin, b_lin, xsr);

    // 6. merged compress k+v (4 chunks each); BM=256, 512-thread blocks
    flash_mfma<<<dim3(4 * NCH, kH, kB * 2), 512, 0, stream>>>(
        xsr, (long)kM * kHD, 0L,
        kh, vh, (long)kH * kN * kHD, (long)kN * kHD,
        kT, vT, (long)kH * kHD * kN, (long)kHD * kN, kN,
        nullptr, 0L, 0L, 0L, 0,
        kN, NCH, 1, Opart, MLpart);
    flash_combine<<<dim3(kM / 4, kH, kB), 256, 0, stream>>>(
        Opart, MLpart, 4, NCH,
        kc, (long)kH * kM * kHD, (long)kM * kHD, 64L, 1);
    // vc written [b,h,m,d] (coalesced stores), then transposed to vcT
    flash_combine<<<dim3(kM / 4, kH, kB), 256, 0, stream>>>(
        Opart + (size_t)1024 * 8192, MLpart + (size_t)1024 * 128, 4, NCH,
        vc, (long)kH * kM * kHD, (long)kM * kHD, 64L, 1);
    transpose_hd<<<dim3(kM / 64, kB * kH, 1), 256, 0, stream>>>(
        (const short*)vc, (const short*)vc, (short*)vcT, (short*)vcT, kM);

    // 7. main attention -> ao fp16 [b][n][h*64+d]; BM=256, 512-thread blocks
    flash_mfma<<<dim3(16, kH, kB), 512, 0, stream>>>(
        qh, (long)kH * kN * kHD, (long)kN * kHD,
        kc, kc, (long)kH * kM * kHD, (long)kM * kHD,
        vcT, vcT, (long)kH * kHD * kM, (long)kHD * kM, kM,
        ao, (long)kN * kC, 64L, (long)kC, 1,
        kM, 1, 0, nullptr, nullptr);

    // 8. proj GEMM (fp16) -> out fp32 (+bias)
    gemm_f16<<<dim3(kC / 128, kB * kN / 128), 256, 0, stream>>>(
        ao, wp16, kB * kN, kC, kC, 0, 1.0f, b_proj, out,
        nullptr, nullptr, nullptr);
}

// Round 11
// 387.621 us; speedup vs baseline: 1.1975x; 1.1975x over previous
//
#include <hip/hip_runtime.h>

typedef float f32x4 __attribute__((ext_vector_type(4)));
typedef short bf16x8 __attribute__((ext_vector_type(8)));
typedef _Float16 f16x8 __attribute__((ext_vector_type(8)));
typedef __fp16 fp16x2 __attribute__((ext_vector_type(2)));

constexpr int kB  = 4;
constexpr int kN  = 4096;
constexpr int kC  = 512;
constexpr int kH  = 8;
constexpr int kHD = 64;
constexpr int kM  = 1024;
constexpr int kC3 = 1536;

// pack 2 floats -> 2 fp16 in one dword (v_cvt_pkrtz_f16_f32, 1 inst)
__device__ inline unsigned pkh(float a, float b) {
    union { fp16x2 h; unsigned u; } u;
    u.h = __builtin_amdgcn_cvt_pkrtz(a, b);
    return u.u;
}

// permlane swaps: exchange quad-rows between two regs (gfx950).
__device__ inline void swap32p(unsigned &a, unsigned &b) {
#if __has_builtin(__builtin_amdgcn_permlane32_swap)
    auto r = __builtin_amdgcn_permlane32_swap(a, b, false, false);
    a = r[0]; b = r[1];
#else
    asm volatile("v_permlane32_swap_b32 %0, %1" : "+v"(a), "+v"(b));
#endif
}
__device__ inline void swap16p(unsigned &a, unsigned &b) {
#if __has_builtin(__builtin_amdgcn_permlane16_swap)
    auto r = __builtin_amdgcn_permlane16_swap(a, b, false, false);
    a = r[0]; b = r[1];
#else
    asm volatile("v_permlane16_swap_b32 %0, %1" : "+v"(a), "+v"(b));
#endif
}

// async global->LDS, 16B per lane. LDS dest = uniform base + lane*16.
__device__ inline void gl_lds16(const _Float16* g, _Float16* l) {
    __builtin_amdgcn_global_load_lds(
        (const __attribute__((address_space(1))) unsigned int*)(const void*)g,
        (__attribute__((address_space(3))) unsigned int*)(void*)l, 16, 0, 0);
}

// ---------------------------------------------------------------------------
// cvt_f16: fp32 -> fp16 flat. n4 = count/4.
// ---------------------------------------------------------------------------
__global__ __launch_bounds__(256) void cvt_f16(
    const float* __restrict__ X, _Float16* __restrict__ Y, int n4)
{
    int i = blockIdx.x * 256 + threadIdx.x;
    if (i >= n4) return;
    float4 v = ((const float4*)X)[i];
    union { _Float16 h[4]; short4 s; } u;
    u.h[0] = (_Float16)v.x; u.h[1] = (_Float16)v.y;
    u.h[2] = (_Float16)v.z; u.h[3] = (_Float16)v.w;
    ((short4*)Y)[i] = u.s;
}

// ---------------------------------------------------------------------------
// wcvtT16: W [K][N] fp32 -> T [N][K] fp16 (transposed)
// ---------------------------------------------------------------------------
__global__ __launch_bounds__(256) void wcvtT16(
    const float* __restrict__ W, int K, int N, _Float16* __restrict__ T16)
{
    __shared__ float T[64][65];
    const int n0 = blockIdx.x * 64, k0 = blockIdx.y * 64;
    const int t = threadIdx.x;
#pragma unroll
    for (int i = 0; i < 4; i++) {
        int c = t + i * 256;
        int row = c >> 4, col4 = (c & 15) * 4;
        *(float4*)&T[row][col4] = *(const float4*)&W[(size_t)(k0 + row) * N + n0 + col4];
    }
    __syncthreads();
#pragma unroll
    for (int i = 0; i < 4; i++) {
        int c = t + i * 256;
        int nrow = c >> 4, kc4 = (c & 15) * 4;
        union { _Float16 h[4]; short4 s; } u;
        u.h[0] = (_Float16)T[kc4 + 0][nrow];
        u.h[1] = (_Float16)T[kc4 + 1][nrow];
        u.h[2] = (_Float16)T[kc4 + 2][nrow];
        u.h[3] = (_Float16)T[kc4 + 3][nrow];
        *(short4*)&T16[(size_t)(n0 + nrow) * K + k0 + kc4] = u.s;
    }
}

// ---------------------------------------------------------------------------
// transpose_hd: [bh][nTok][64] -> [bh][64][nTok], 2 arrays (bit-agnostic 16b).
// ---------------------------------------------------------------------------
__global__ __launch_bounds__(256) void transpose_hd(
    const short* __restrict__ s0, const short* __restrict__ s1,
    short* __restrict__ d0, short* __restrict__ d1, int nTok)
{
    __shared__ short T[64][72];
    const short* src = blockIdx.z == 0 ? s0 : s1;
    short*       dst = blockIdx.z == 0 ? d0 : d1;
    const int n0 = blockIdx.x * 64, bh = blockIdx.y;
    const int t = threadIdx.x;
#pragma unroll
    for (int i = 0; i < 2; i++) {
        int c = t + i * 256;
        int row = c >> 3, j = (c & 7) * 8;
        *(bf16x8*)&T[row][j] = *(const bf16x8*)&src[((size_t)bh * nTok + n0 + row) * 64 + j];
    }
    __syncthreads();
#pragma unroll
    for (int i = 0; i < 2; i++) {
        int c = t + i * 256;
        int drow = c >> 3, j = (c & 7) * 8;
        bf16x8 v;
#pragma unroll
        for (int q = 0; q < 8; q++) v[q] = T[j + q][drow];
        *(bf16x8*)&dst[((size_t)bh * 64 + drow) * nTok + n0 + j] = v;
    }
}

// ---------------------------------------------------------------------------
// gemm_f16: C[Md,Nd] = A[Md,Kd] @ B^T[Nd,Kd], fp16 in, fp32 accumulate.
// mode 0: Cf[row][col] = acc + bias (fp32). mode 1: qkv scatter to fp16,
// with q pre-scaled by qscale. 128x128 tile, BK=32, 4 waves.
// Staging via async global_load_lds width=16 (m97 structure).
// ---------------------------------------------------------------------------
__global__ __launch_bounds__(256) void gemm_f16(
    const _Float16* __restrict__ A, const _Float16* __restrict__ B,
    int Md, int Nd, int Kd, int mode, float qscale,
    const float* __restrict__ bias, float* __restrict__ Cf,
    _Float16* __restrict__ q, _Float16* __restrict__ k, _Float16* __restrict__ v)
{
    __shared__ _Float16 Ash[128][32], Bsh[128][32];
    const int t = threadIdx.x, lane = t & 63, L = lane & 15, quad = lane >> 4;
    const int wave = t >> 6, wm = wave >> 1, wn = wave & 1;
    const int bm = blockIdx.y * 128, bn = blockIdx.x * 128;
    const int r16 = lane >> 2, c16 = lane & 3;   // staging: row-in-chunk, col16

    f32x4 acc[4][4];
#pragma unroll
    for (int i = 0; i < 4; i++)
#pragma unroll
        for (int j = 0; j < 4; j++) acc[i][j] = (f32x4){0.f, 0.f, 0.f, 0.f};

    for (int k0 = 0; k0 < Kd; k0 += 32) {
#pragma unroll
        for (int i = 0; i < 2; i++) {
            int chunk = wave * 2 + i;          // 8 chunks of 16 rows
            int row = chunk * 16 + r16;
            gl_lds16(&A[(size_t)(bm + row) * Kd + k0 + c16 * 8], &Ash[chunk * 16][0]);
            gl_lds16(&B[(size_t)(bn + row) * Kd + k0 + c16 * 8], &Bsh[chunk * 16][0]);
        }
        __syncthreads();
        f16x8 af[4];
#pragma unroll
        for (int mi = 0; mi < 4; mi++)
            af[mi] = *(const f16x8*)&Ash[wm * 64 + mi * 16 + L][quad * 8];
#pragma unroll
        for (int ni = 0; ni < 4; ni++) {
            f16x8 bf = *(const f16x8*)&Bsh[wn * 64 + ni * 16 + L][quad * 8];
#pragma unroll
            for (int mi = 0; mi < 4; mi++)
                acc[mi][ni] = __builtin_amdgcn_mfma_f32_16x16x32_f16(af[mi], bf, acc[mi][ni], 0, 0, 0);
        }
        __syncthreads();
    }

    if (mode == 0) {
#pragma unroll
        for (int ni = 0; ni < 4; ni++) {
            int col = bn + wn * 64 + ni * 16 + L;
            float bb = bias ? bias[col] : 0.f;
#pragma unroll
            for (int mi = 0; mi < 4; mi++)
#pragma unroll
                for (int r = 0; r < 4; r++) {
                    int row = bm + wm * 64 + mi * 16 + quad * 4 + r;
                    Cf[(size_t)row * Nd + col] = acc[mi][ni][r] + bb;
                }
        }
    } else {
#pragma unroll
        for (int ni = 0; ni < 4; ni++) {
            int col = bn + wn * 64 + ni * 16 + L;
            int s = col >> 9, h = (col >> 6) & 7, d = col & 63;
            _Float16* dst = s == 0 ? q : s == 1 ? k : v;
            float sc = (s == 0) ? qscale : 1.0f;
#pragma unroll
            for (int mi = 0; mi < 4; mi++)
#pragma unroll
                for (int r = 0; r < 4; r++) {
                    int row = bm + wm * 64 + mi * 16 + quad * 4 + r;
                    int b = row >> 12, n = row & 4095;
                    size_t idx = (((size_t)b * 8 + h) * 4096 + n) * 64 + d;
                    dst[idx] = (_Float16)(acc[mi][ni][r] * sc);
                }
        }
    }
}

// ---------------------------------------------------------------------------
// sr_fused: depthwise 2x2/s2 conv + LayerNorm + linear -> xsr fp16.
// Output pre-scaled by log2e (softmax scale fold, f32-side, rounding-neutral).
// ---------------------------------------------------------------------------
__global__ __launch_bounds__(256) void sr_fused(
    const float* __restrict__ x, const float* __restrict__ wconv,
    const float* __restrict__ bconv, const float* __restrict__ gamma,
    const float* __restrict__ beta, const float* __restrict__ wlin,
    const float* __restrict__ blin, _Float16* __restrict__ xsr)
{
    __shared__ float nbuf[512];
    __shared__ float red[8];
    __shared__ float stats[2];
    __shared__ float pbuf[4][64];

    const int m = blockIdx.x, b = blockIdx.y;
    const int oy = m >> 5, ox = m & 31;
    const int t = threadIdx.x;
    const float* xb = x + (size_t)b * kN * kC;

    float vals[2], s = 0.f, sq = 0.f;
#pragma unroll
    for (int i = 0; i < 2; i++) {
        int c = t + i * 256;
        float acc = bconv[c];
#pragma unroll
        for (int dy = 0; dy < 2; dy++)
#pragma unroll
            for (int dx = 0; dx < 2; dx++) {
                int n = (oy * 2 + dy) * 64 + (ox * 2 + dx);
                acc += xb[(size_t)n * kC + c] * wconv[c * 4 + dy * 2 + dx];
            }
        vals[i] = acc;
        s += acc; sq += acc * acc;
    }
#pragma unroll
    for (int off = 32; off > 0; off >>= 1) {
        s  += __shfl_down(s,  off);
        sq += __shfl_down(sq, off);
    }
    if ((t & 63) == 0) { red[t >> 6] = s; red[4 + (t >> 6)] = sq; }
    __syncthreads();
    if (t == 0) {
        float ts = red[0] + red[1] + red[2] + red[3];
        float tq = red[4] + red[5] + red[6] + red[7];
        float mean = ts * (1.f / 512.f);
        float var  = tq * (1.f / 512.f) - mean * mean;
        stats[0] = mean;
        stats[1] = rsqrtf(var + 1e-5f);
    }
    __syncthreads();
    const float mean = stats[0], rstd = stats[1];
#pragma unroll
    for (int i = 0; i < 2; i++) {
        int c = t + i * 256;
        nbuf[c] = (vals[i] - mean) * rstd * gamma[c] + beta[c];
    }
    __syncthreads();
    const int d = t & 63, part = t >> 6;
    float p = 0.f;
    for (int c = part * 128; c < (part + 1) * 128; c++)
        p += nbuf[c] * wlin[c * 64 + d];
    pbuf[part][d] = p;
    __syncthreads();
    if (t < 64) {
        float o = pbuf[0][t] + pbuf[1][t] + pbuf[2][t] + pbuf[3][t] + blin[t];
        xsr[((size_t)b * kM + m) * kHD + t] = (_Float16)(o * 1.44269504089f);
    }
}

// ---------------------------------------------------------------------------
// MFMA flash attention, fp16, transposed-S, in-register P^T via permlane
// swaps, double-buffered LDS, ONE barrier per tile, XCD-aware work remap.
// BM=256, 8 waves / 512 threads, launch_bounds(512,4) (VGPR cap 128; actual
// ~57 -> 8 waves/SIMD possible; LDS 36,864 B -> 4 blocks/CU).
// ROW-SUM VIA ONES-MFMA: Lacc[s] += mfma(onesA, pt[s][h2]) gives
// D[*][m] = sum_k P^T[k][m] (all rows equal, A=all-ones is layout-free) ->
// lt[s] = Lacc[s][0] with NO per-element dot2 and NO cross-lane reduce.
// Replaces 16 v_dot2/tile (VALU) with 4 MFMA/tile (matrix pipe at 24%).
// ---------------------------------------------------------------------------
__global__ __launch_bounds__(512, 4) void flash_mfma(
    const _Float16* __restrict__ Q, long q_bs, long q_hs,
    const _Float16* __restrict__ K0, const _Float16* __restrict__ K1,
    long k_bs, long k_hs,
    const _Float16* __restrict__ VT0, const _Float16* __restrict__ VT1,
    long v_bs, long v_hs, int v_rs,
    _Float16* __restrict__ O,
    long o_bs, long o_hs, long o_rs, int o_cs,
    int nKtot, int nChunks, int kvMerge,
    _Float16* __restrict__ Opart, float* __restrict__ MLpart)
{
    __shared__ _Float16 Ks[2][64][72];
    __shared__ _Float16 VTs[2][64][72];
    const int t = threadIdx.x, lane = t & 63, L = lane & 15, quad = lane >> 4;
    const int wave = t >> 6;                       // 0..7
    // XCD-aware remap. Bijective over (x,y); requires gridDim.y==8, gx%8==0.
    const int h = blockIdx.x & 7;
    const int rest = (blockIdx.x >> 3) + (gridDim.x >> 3) * blockIdx.y;
    int b, which, nB;
    if (kvMerge) { b = blockIdx.z >> 1; which = blockIdx.z & 1; nB = gridDim.z >> 1; }
    else         { b = blockIdx.z;      which = 0;              nB = gridDim.z; }
    const int nMblk = gridDim.x / nChunks;
    const int mblk = rest / nChunks, chunk = rest % nChunks;
    const int m0 = mblk * 256;
    const int nkc = nKtot / nChunks, nbeg = chunk * nkc, nend = nbeg + nkc;

    const _Float16* K_ = (which ? K1 : K0) + (size_t)b * k_bs + (size_t)h * k_hs;
    const _Float16* V_ = (which ? VT1 : VT0) + (size_t)b * v_bs + (size_t)h * v_hs;

    // all-ones A-fragment for the row-sum MFMA (layout-independent)
    f16x8 onesA;
#pragma unroll
    for (int i = 0; i < 8; i++) onesA[i] = (_Float16)1.0f;

    // Q as B-fragments (each wave owns rows m0 + wave*32 + s*16 + L)
    f16x8 qf[2][2];
#pragma unroll
    for (int s = 0; s < 2; s++) {
        const size_t qrow = (size_t)b * q_bs + (size_t)h * q_hs
                          + (size_t)(m0 + wave * 32 + s * 16 + L) * 64;
        qf[s][0] = *(const f16x8*)&Q[qrow + quad * 8];
        qf[s][1] = *(const f16x8*)&Q[qrow + 32 + quad * 8];
    }

    f32x4 Oacc[2][4];
    f32x4 Lacc[2];
#pragma unroll
    for (int s = 0; s < 2; s++) {
#pragma unroll
        for (int i = 0; i < 4; i++) Oacc[s][i] = (f32x4){0.f, 0.f, 0.f, 0.f};
        Lacc[s] = (f32x4){0.f, 0.f, 0.f, 0.f};
    }

    // staging geometry: 512 threads cover [64][64] once: row t>>3, col (t&7)*8
    const int sr = t >> 3, sj = (t & 7) * 8;

    // prologue: stage tile nbeg into buffer 0
    {
        f16x8 a0 = *(const f16x8*)&K_[(size_t)(nbeg + sr) * 64 + sj];
        f16x8 a2 = *(const f16x8*)&V_[(size_t)sr * v_rs + nbeg + sj];
        *(f16x8*)&Ks[0][sr][sj]  = a0;
        *(f16x8*)&VTs[0][sr][sj] = a2;
    }
    __syncthreads();

    int cur = 0;
    for (int n0 = nbeg; n0 < nend; n0 += 64) {
        // issue next tile's global loads (latency hidden under compute)
        int nn = (n0 + 64 < nend) ? n0 + 64 : nbeg;
        f16x8 kp0 = *(const f16x8*)&K_[(size_t)(nn + sr) * 64 + sj];
        f16x8 vp0 = *(const f16x8*)&V_[(size_t)sr * v_rs + nn + sj];

        // QK^T (S^T layout) fused with softmax exp + fp16 pack.
        unsigned d0[2][4], d1[2][4];
#pragma unroll
        for (int c = 0; c < 4; c++) {
            f16x8 k0 = *(const f16x8*)&Ks[cur][c * 16 + L][quad * 8];
            f16x8 k1 = *(const f16x8*)&Ks[cur][c * 16 + L][32 + quad * 8];
#pragma unroll
            for (int s = 0; s < 2; s++) {
                f32x4 a = (f32x4){0.f, 0.f, 0.f, 0.f};
                a = __builtin_amdgcn_mfma_f32_16x16x32_f16(k0, qf[s][0], a, 0, 0, 0);
                a = __builtin_amdgcn_mfma_f32_16x16x32_f16(k1, qf[s][1], a, 0, 0, 0);
                float p0 = exp2f(a[0]);
                float p1 = exp2f(a[1]);
                float p2 = exp2f(a[2]);
                float p3 = exp2f(a[3]);
                d0[s][c] = pkh(p0, p1);
                d1[s][c] = pkh(p2, p3);
            }
        }

        // in-register P^T: build B-fragments pt[s][h2]
        f16x8 pt[2][2];
#pragma unroll
        for (int s = 0; s < 2; s++)
#pragma unroll
            for (int h2 = 0; h2 < 2; h2++) {
                unsigned a0 = d0[s][h2 * 2], b0 = d0[s][h2 * 2 + 1];
                swap32p(a0, b0); swap16p(a0, b0);
                unsigned a1 = d1[s][h2 * 2], b1 = d1[s][h2 * 2 + 1];
                swap32p(a1, b1); swap16p(a1, b1);
                union { unsigned u[4]; f16x8 v; } U;
                U.u[0] = a0; U.u[1] = a1; U.u[2] = b0; U.u[3] = b1;
                pt[s][h2] = U.v;
            }

#pragma unroll
        for (int h2 = 0; h2 < 2; h2++) {
#pragma unroll
            for (int dch = 0; dch < 4; dch++) {
                f16x8 vt = *(const f16x8*)&VTs[cur][dch * 16 + L][h2 * 32 + quad * 8];
                Oacc[0][dch] = __builtin_amdgcn_mfma_f32_16x16x32_f16(vt, pt[0][h2], Oacc[0][dch], 0, 0, 0);
                Oacc[1][dch] = __builtin_amdgcn_mfma_f32_16x16x32_f16(vt, pt[1][h2], Oacc[1][dch], 0, 0, 0);
            }
            // row-sum: D[*][m] = sum_k P^T[k][m]
            Lacc[0] = __builtin_amdgcn_mfma_f32_16x16x32_f16(onesA, pt[0][h2], Lacc[0], 0, 0, 0);
            Lacc[1] = __builtin_amdgcn_mfma_f32_16x16x32_f16(onesA, pt[1][h2], Lacc[1], 0, 0, 0);
        }

        // stage tile i+1 into the alternate buffer (WAR-safe: its readers
        // finished before the previous barrier)
        *(f16x8*)&Ks[cur ^ 1][sr][sj]  = kp0;
        *(f16x8*)&VTs[cur ^ 1][sr][sj] = vp0;
        __syncthreads();
        cur ^= 1;
    }

    // row-sums are complete per-lane (all D-rows equal; col = query L)
    float lt[2] = { Lacc[0][0], Lacc[1][0] };

    if (Opart) {
        int pid = (((which * nB + b) * gridDim.y + h) * nMblk + mblk) * nChunks + chunk;
        _Float16* Ob = Opart + (size_t)pid * (256 * 64);
        float* Mb = MLpart + (size_t)pid * 256;
#pragma unroll
        for (int s = 0; s < 2; s++) {
            int mloc = wave * 32 + s * 16 + L;
            float inv = 1.f / lt[s];
#pragma unroll
            for (int dch = 0; dch < 4; dch++) {
                union { _Float16 h[4]; uint2 u; } U;
#pragma unroll
                for (int r = 0; r < 4; r++)
                    U.h[r] = (_Float16)(Oacc[s][dch][r] * inv);
                *(uint2*)&Ob[mloc * 64 + dch * 16 + quad * 4] = U.u;
            }
            if (quad == 0) Mb[mloc] = lt[s];
        }
    } else {
#pragma unroll
        for (int s = 0; s < 2; s++) {
            float inv = 1.f / lt[s];
            size_t base = (size_t)b * o_bs + (size_t)h * o_hs
                        + (size_t)(m0 + wave * 32 + s * 16 + L) * o_rs;
#pragma unroll
            for (int dch = 0; dch < 4; dch++)
#pragma unroll
                for (int r = 0; r < 4; r++) {
                    int d = dch * 16 + quad * 4 + r;
                    O[base + (size_t)d * o_cs] = (_Float16)(Oacc[s][dch][r] * inv);
                }
        }
    }
}

// ---------------------------------------------------------------------------
// flash_combine: merge nChunks normalized fp16 partials, weighted by l.
// MERGED k+v: grid (M/4, H, 2*B); z < B -> O0 (kc), z >= B -> O1 (vc).
// Both outputs share layout [b][h][m][d] (o_bs, o_hs, row stride 64).
// Per-pid Opart 256x64 fp16, MLpart 256 floats (BM=256 partials).
// ---------------------------------------------------------------------------
__global__ __launch_bounds__(256) void flash_combine(
    const _Float16* __restrict__ Opart, const float* __restrict__ MLpart,
    int nMblk, int nChunks,
    _Float16* __restrict__ O0, _Float16* __restrict__ O1,
    long o_bs, long o_hs)
{
    const int t = threadIdx.x;
    const int zz = blockIdx.z, h = blockIdx.y;
    const int nB = gridDim.z >> 1;
    const int which = zz >= nB ? 1 : 0;
    const int b = which ? zz - nB : zz;
    _Float16* O = which ? O1 : O0;
    const int qm = blockIdx.x * 4 + (t >> 6), d = t & 63;
    const int mblk = qm >> 8, qloc = qm & 255;
    const int pb = (((which * nB + b) * gridDim.y + h) * nMblk + mblk) * nChunks;
    float num = 0.f, den = 0.f;
    for (int c = 0; c < nChunks; c++) {
        float lc = MLpart[(size_t)(pb + c) * 256 + qloc];
        num += lc * (float)Opart[(size_t)(pb + c) * 16384 + qloc * 64 + d];
        den += lc;
    }
    O[(size_t)b * o_bs + (size_t)h * o_hs + (size_t)qm * 64 + d] = (_Float16)(num / den);
}

// ---------------------------------------------------------------------------
extern "C" void kernel_launch(void* const* d_in, const int* in_sizes, int n_in,
                              void* d_out, int out_size, void* d_ws, size_t ws_size,
                              hipStream_t stream)
{
    const float* x      = (const float*)d_in[0];
    const float* w_qkv  = (const float*)d_in[1];
    const float* w_proj = (const float*)d_in[2];
    const float* b_proj = (const float*)d_in[3];
    const float* w_conv = (const float*)d_in[4];
    const float* b_conv = (const float*)d_in[5];
    const float* g_ln   = (const float*)d_in[6];
    const float* b_ln   = (const float*)d_in[7];
    const float* w_lin  = (const float*)d_in[8];
    const float* b_lin  = (const float*)d_in[9];
    float* out = (float*)d_out;
    (void)in_sizes; (void)n_in; (void)out_size; (void)ws_size;

    short* p = (short*)d_ws;
    size_t off = 0;
    auto alloc = [&](size_t n) { short* r = p + off; off += n; return r; };

    const size_t TN = (size_t)kB * kH * kN * kHD;   // 8.39M elems
    const size_t TM = (size_t)kB * kH * kM * kHD;   // 2.10M elems

    // region0: xf16, later ao (both fp16, lifetimes disjoint)
    _Float16* xf16 = (_Float16*)alloc((size_t)kB * kN * kC);
    _Float16* ao   = xf16;

    _Float16* wq16 = (_Float16*)alloc((size_t)kC3 * kC);
    _Float16* wp16 = (_Float16*)alloc((size_t)kC * kC);
    _Float16* qh  = (_Float16*)alloc(TN);
    _Float16* kh  = (_Float16*)alloc(TN);
    _Float16* vh  = (_Float16*)alloc(TN);
    _Float16* kT  = (_Float16*)alloc(TN);
    _Float16* vT  = (_Float16*)alloc(TN);
    _Float16* xsr = (_Float16*)alloc((size_t)kB * kM * kHD);
    _Float16* kc  = (_Float16*)alloc(TM);
    _Float16* vc  = (_Float16*)alloc(TM);   // [b,h,m,d] coalesced combine out
    _Float16* vcT = (_Float16*)alloc(TM);   // [b,h,d,m] for PV staging
    float*    MLpart = (float*)alloc((size_t)2048 * 128 * 2);
    _Float16* Opart  = (_Float16*)alloc((size_t)2048 * 8192);  // fp16 partials

    const int NCH = 4;   // compress key-chunks

    // 1. x -> fp16
    cvt_f16<<<(kB * kN * kC / 4 + 255) / 256, 256, 0, stream>>>(
        x, xf16, kB * kN * kC / 4);

    // 2. weights -> fp16 transposed
    wcvtT16<<<dim3(kC3 / 64, kC / 64), 256, 0, stream>>>(w_qkv, kC, kC3, wq16);
    wcvtT16<<<dim3(kC / 64, kC / 64), 256, 0, stream>>>(w_proj, kC, kC, wp16);

    // 3. qkv GEMM (fp16) -> q,k,v fp16 [b,h,n,d]; q pre-scaled by
    //    attn_scale*log2e = 0.125*1.4427
    gemm_f16<<<dim3(kC3 / 128, kB * kN / 128), 256, 0, stream>>>(
        xf16, wq16, kB * kN, kC3, kC, 1, 0.18033688f, nullptr, nullptr,
        qh, kh, vh);

    // 4. k,v -> kT,vT ([b,h,d,n])
    transpose_hd<<<dim3(kN / 64, kB * kH, 2), 256, 0, stream>>>(
        (const short*)kh, (const short*)vh, (short*)kT, (short*)vT, kN);

    // 5. SR branch -> xsr fp16 (pre-scaled by log2e)
    sr_fused<<<dim3(kM, kB), 256, 0, stream>>>(
        x, w_conv, b_conv, g_ln, b_ln, w_lin, b_lin, xsr);

    // 6. merged compress k+v (4 chunks each); BM=256, 512-thread blocks
    flash_mfma<<<dim3(4 * NCH, kH, kB * 2), 512, 0, stream>>>(
        xsr, (long)kM * kHD, 0L,
        kh, vh, (long)kH * kN * kHD, (long)kN * kHD,
        kT, vT, (long)kH * kHD * kN, (long)kHD * kN, kN,
        nullptr, 0L, 0L, 0L, 0,
        kN, NCH, 1, Opart, MLpart);
    // merged combine: z<B -> kc, z>=B -> vc (both [b,h,m,d])
    flash_combine<<<dim3(kM / 4, kH, kB * 2), 256, 0, stream>>>(
        Opart, MLpart, 4, NCH,
        kc, vc, (long)kH * kM * kHD, (long)kM * kHD);
    transpose_hd<<<dim3(kM / 64, kB * kH, 1), 256, 0, stream>>>(
        (const short*)vc, (const short*)vc, (short*)vcT, (short*)vcT, kM);

    // 7. main attention -> ao fp16 [b][n][h*64+d]; BM=256, 512-thread blocks
    flash_mfma<<<dim3(16, kH, kB), 512, 0, stream>>>(
        qh, (long)kH * kN * kHD, (long)kN * kHD,
        kc, kc, (long)kH * kM * kHD, (long)kM * kHD,
        vcT, vcT, (long)kH * kHD * kM, (long)kHD * kM, kM,
        ao, (long)kN * kC, 64L, (long)kC, 1,
        kM, 1, 0, nullptr, nullptr);

    // 8. proj GEMM (fp16) -> out fp32 (+bias)
    gemm_f16<<<dim3(kC / 128, kB * kN / 128), 256, 0, stream>>>(
        ao, wp16, kB * kN, kC, kC, 0, 1.0f, b_proj, out,
        nullptr, nullptr, nullptr);
}

// Round 12
// 353.829 us; speedup vs baseline: 1.3119x; 1.0955x over previous
//
#include <hip/hip_runtime.h>

typedef float f32x4 __attribute__((ext_vector_type(4)));
typedef short bf16x8 __attribute__((ext_vector_type(8)));
typedef _Float16 f16x8 __attribute__((ext_vector_type(8)));
typedef __fp16 fp16x2 __attribute__((ext_vector_type(2)));

constexpr int kB  = 4;
constexpr int kN  = 4096;
constexpr int kC  = 512;
constexpr int kH  = 8;
constexpr int kHD = 64;
constexpr int kM  = 1024;
constexpr int kC3 = 1536;

// native hardware exp2: ONE v_exp_f32 (quarter-rate) instead of the OCML
// correctly-rounded polynomial (~20 VALU insts) that plain exp2f() lowers to
// without -ffast-math. ~1 ulp, irrelevant vs the fp16 truncation of P.
__device__ inline float nexp2(float x) {
#if __has_builtin(__builtin_amdgcn_exp2f)
    return __builtin_amdgcn_exp2f(x);
#else
    float r;
    asm("v_exp_f32 %0, %1" : "=v"(r) : "v"(x));
    return r;
#endif
}

// pack 2 floats -> 2 fp16 in one dword (v_cvt_pkrtz_f16_f32, 1 inst)
__device__ inline unsigned pkh(float a, float b) {
    union { fp16x2 h; unsigned u; } u;
    u.h = __builtin_amdgcn_cvt_pkrtz(a, b);
    return u.u;
}

// permlane swaps: exchange quad-rows between two regs (gfx950).
__device__ inline void swap32p(unsigned &a, unsigned &b) {
#if __has_builtin(__builtin_amdgcn_permlane32_swap)
    auto r = __builtin_amdgcn_permlane32_swap(a, b, false, false);
    a = r[0]; b = r[1];
#else
    asm volatile("v_permlane32_swap_b32 %0, %1" : "+v"(a), "+v"(b));
#endif
}
__device__ inline void swap16p(unsigned &a, unsigned &b) {
#if __has_builtin(__builtin_amdgcn_permlane16_swap)
    auto r = __builtin_amdgcn_permlane16_swap(a, b, false, false);
    a = r[0]; b = r[1];
#else
    asm volatile("v_permlane16_swap_b32 %0, %1" : "+v"(a), "+v"(b));
#endif
}

// async global->LDS, 16B per lane. LDS dest = uniform base + lane*16.
__device__ inline void gl_lds16(const _Float16* g, _Float16* l) {
    __builtin_amdgcn_global_load_lds(
        (const __attribute__((address_space(1))) unsigned int*)(const void*)g,
        (__attribute__((address_space(3))) unsigned int*)(void*)l, 16, 0, 0);
}

// ---------------------------------------------------------------------------
// cvt_f16: fp32 -> fp16 flat. n4 = count/4.
// ---------------------------------------------------------------------------
__global__ __launch_bounds__(256) void cvt_f16(
    const float* __restrict__ X, _Float16* __restrict__ Y, int n4)
{
    int i = blockIdx.x * 256 + threadIdx.x;
    if (i >= n4) return;
    float4 v = ((const float4*)X)[i];
    union { _Float16 h[4]; short4 s; } u;
    u.h[0] = (_Float16)v.x; u.h[1] = (_Float16)v.y;
    u.h[2] = (_Float16)v.z; u.h[3] = (_Float16)v.w;
    ((short4*)Y)[i] = u.s;
}

// ---------------------------------------------------------------------------
// wcvtT16: W [K][N] fp32 -> T [N][K] fp16 (transposed)
// ---------------------------------------------------------------------------
__global__ __launch_bounds__(256) void wcvtT16(
    const float* __restrict__ W, int K, int N, _Float16* __restrict__ T16)
{
    __shared__ float T[64][65];
    const int n0 = blockIdx.x * 64, k0 = blockIdx.y * 64;
    const int t = threadIdx.x;
#pragma unroll
    for (int i = 0; i < 4; i++) {
        int c = t + i * 256;
        int row = c >> 4, col4 = (c & 15) * 4;
        *(float4*)&T[row][col4] = *(const float4*)&W[(size_t)(k0 + row) * N + n0 + col4];
    }
    __syncthreads();
#pragma unroll
    for (int i = 0; i < 4; i++) {
        int c = t + i * 256;
        int nrow = c >> 4, kc4 = (c & 15) * 4;
        union { _Float16 h[4]; short4 s; } u;
        u.h[0] = (_Float16)T[kc4 + 0][nrow];
        u.h[1] = (_Float16)T[kc4 + 1][nrow];
        u.h[2] = (_Float16)T[kc4 + 2][nrow];
        u.h[3] = (_Float16)T[kc4 + 3][nrow];
        *(short4*)&T16[(size_t)(n0 + nrow) * K + k0 + kc4] = u.s;
    }
}

// ---------------------------------------------------------------------------
// transpose_hd: [bh][nTok][64] -> [bh][64][nTok], 2 arrays (bit-agnostic 16b).
// ---------------------------------------------------------------------------
__global__ __launch_bounds__(256) void transpose_hd(
    const short* __restrict__ s0, const short* __restrict__ s1,
    short* __restrict__ d0, short* __restrict__ d1, int nTok)
{
    __shared__ short T[64][72];
    const short* src = blockIdx.z == 0 ? s0 : s1;
    short*       dst = blockIdx.z == 0 ? d0 : d1;
    const int n0 = blockIdx.x * 64, bh = blockIdx.y;
    const int t = threadIdx.x;
#pragma unroll
    for (int i = 0; i < 2; i++) {
        int c = t + i * 256;
        int row = c >> 3, j = (c & 7) * 8;
        *(bf16x8*)&T[row][j] = *(const bf16x8*)&src[((size_t)bh * nTok + n0 + row) * 64 + j];
    }
    __syncthreads();
#pragma unroll
    for (int i = 0; i < 2; i++) {
        int c = t + i * 256;
        int drow = c >> 3, j = (c & 7) * 8;
        bf16x8 v;
#pragma unroll
        for (int q = 0; q < 8; q++) v[q] = T[j + q][drow];
        *(bf16x8*)&dst[((size_t)bh * 64 + drow) * nTok + n0 + j] = v;
    }
}

// ---------------------------------------------------------------------------
// gemm_f16: C[Md,Nd] = A[Md,Kd] @ B^T[Nd,Kd], fp16 in, fp32 accumulate.
// mode 0: Cf[row][col] = acc + bias (fp32). mode 1: qkv scatter to fp16,
// with q pre-scaled by qscale. 128x128 tile, BK=32, 4 waves.
// Staging via async global_load_lds width=16 (m97 structure).
// ---------------------------------------------------------------------------
__global__ __launch_bounds__(256) void gemm_f16(
    const _Float16* __restrict__ A, const _Float16* __restrict__ B,
    int Md, int Nd, int Kd, int mode, float qscale,
    const float* __restrict__ bias, float* __restrict__ Cf,
    _Float16* __restrict__ q, _Float16* __restrict__ k, _Float16* __restrict__ v)
{
    __shared__ _Float16 Ash[128][32], Bsh[128][32];
    const int t = threadIdx.x, lane = t & 63, L = lane & 15, quad = lane >> 4;
    const int wave = t >> 6, wm = wave >> 1, wn = wave & 1;
    const int bm = blockIdx.y * 128, bn = blockIdx.x * 128;
    const int r16 = lane >> 2, c16 = lane & 3;   // staging: row-in-chunk, col16

    f32x4 acc[4][4];
#pragma unroll
    for (int i = 0; i < 4; i++)
#pragma unroll
        for (int j = 0; j < 4; j++) acc[i][j] = (f32x4){0.f, 0.f, 0.f, 0.f};

    for (int k0 = 0; k0 < Kd; k0 += 32) {
#pragma unroll
        for (int i = 0; i < 2; i++) {
            int chunk = wave * 2 + i;          // 8 chunks of 16 rows
            int row = chunk * 16 + r16;
            gl_lds16(&A[(size_t)(bm + row) * Kd + k0 + c16 * 8], &Ash[chunk * 16][0]);
            gl_lds16(&B[(size_t)(bn + row) * Kd + k0 + c16 * 8], &Bsh[chunk * 16][0]);
        }
        __syncthreads();
        f16x8 af[4];
#pragma unroll
        for (int mi = 0; mi < 4; mi++)
            af[mi] = *(const f16x8*)&Ash[wm * 64 + mi * 16 + L][quad * 8];
#pragma unroll
        for (int ni = 0; ni < 4; ni++) {
            f16x8 bf = *(const f16x8*)&Bsh[wn * 64 + ni * 16 + L][quad * 8];
#pragma unroll
            for (int mi = 0; mi < 4; mi++)
                acc[mi][ni] = __builtin_amdgcn_mfma_f32_16x16x32_f16(af[mi], bf, acc[mi][ni], 0, 0, 0);
        }
        __syncthreads();
    }

    if (mode == 0) {
#pragma unroll
        for (int ni = 0; ni < 4; ni++) {
            int col = bn + wn * 64 + ni * 16 + L;
            float bb = bias ? bias[col] : 0.f;
#pragma unroll
            for (int mi = 0; mi < 4; mi++)
#pragma unroll
                for (int r = 0; r < 4; r++) {
                    int row = bm + wm * 64 + mi * 16 + quad * 4 + r;
                    Cf[(size_t)row * Nd + col] = acc[mi][ni][r] + bb;
                }
        }
    } else {
#pragma unroll
        for (int ni = 0; ni < 4; ni++) {
            int col = bn + wn * 64 + ni * 16 + L;
            int s = col >> 9, h = (col >> 6) & 7, d = col & 63;
            _Float16* dst = s == 0 ? q : s == 1 ? k : v;
            float sc = (s == 0) ? qscale : 1.0f;
#pragma unroll
            for (int mi = 0; mi < 4; mi++)
#pragma unroll
                for (int r = 0; r < 4; r++) {
                    int row = bm + wm * 64 + mi * 16 + quad * 4 + r;
                    int b = row >> 12, n = row & 4095;
                    size_t idx = (((size_t)b * 8 + h) * 4096 + n) * 64 + d;
                    dst[idx] = (_Float16)(acc[mi][ni][r] * sc);
                }
        }
    }
}

// ---------------------------------------------------------------------------
// sr_fused: depthwise 2x2/s2 conv + LayerNorm + linear -> xsr fp16.
// Output pre-scaled by log2e (softmax scale fold, f32-side, rounding-neutral).
// ---------------------------------------------------------------------------
__global__ __launch_bounds__(256) void sr_fused(
    const float* __restrict__ x, const float* __restrict__ wconv,
    const float* __restrict__ bconv, const float* __restrict__ gamma,
    const float* __restrict__ beta, const float* __restrict__ wlin,
    const float* __restrict__ blin, _Float16* __restrict__ xsr)
{
    __shared__ float nbuf[512];
    __shared__ float red[8];
    __shared__ float stats[2];
    __shared__ float pbuf[4][64];

    const int m = blockIdx.x, b = blockIdx.y;
    const int oy = m >> 5, ox = m & 31;
    const int t = threadIdx.x;
    const float* xb = x + (size_t)b * kN * kC;

    float vals[2], s = 0.f, sq = 0.f;
#pragma unroll
    for (int i = 0; i < 2; i++) {
        int c = t + i * 256;
        float acc = bconv[c];
#pragma unroll
        for (int dy = 0; dy < 2; dy++)
#pragma unroll
            for (int dx = 0; dx < 2; dx++) {
                int n = (oy * 2 + dy) * 64 + (ox * 2 + dx);
                acc += xb[(size_t)n * kC + c] * wconv[c * 4 + dy * 2 + dx];
            }
        vals[i] = acc;
        s += acc; sq += acc * acc;
    }
#pragma unroll
    for (int off = 32; off > 0; off >>= 1) {
        s  += __shfl_down(s,  off);
        sq += __shfl_down(sq, off);
    }
    if ((t & 63) == 0) { red[t >> 6] = s; red[4 + (t >> 6)] = sq; }
    __syncthreads();
    if (t == 0) {
        float ts = red[0] + red[1] + red[2] + red[3];
        float tq = red[4] + red[5] + red[6] + red[7];
        float mean = ts * (1.f / 512.f);
        float var  = tq * (1.f / 512.f) - mean * mean;
        stats[0] = mean;
        stats[1] = rsqrtf(var + 1e-5f);
    }
    __syncthreads();
    const float mean = stats[0], rstd = stats[1];
#pragma unroll
    for (int i = 0; i < 2; i++) {
        int c = t + i * 256;
        nbuf[c] = (vals[i] - mean) * rstd * gamma[c] + beta[c];
    }
    __syncthreads();
    const int d = t & 63, part = t >> 6;
    float p = 0.f;
    for (int c = part * 128; c < (part + 1) * 128; c++)
        p += nbuf[c] * wlin[c * 64 + d];
    pbuf[part][d] = p;
    __syncthreads();
    if (t < 64) {
        float o = pbuf[0][t] + pbuf[1][t] + pbuf[2][t] + pbuf[3][t] + blin[t];
        xsr[((size_t)b * kM + m) * kHD + t] = (_Float16)(o * 1.44269504089f);
    }
}

// ---------------------------------------------------------------------------
// MFMA flash attention, fp16, transposed-S, in-register P^T via permlane
// swaps, double-buffered LDS, ONE barrier per tile, XCD-aware work remap.
// BM=256, 8 waves / 512 threads, launch_bounds(512,4).
// p = nexp2(a): NATIVE v_exp_f32 (1 inst) — plain exp2f() lowers to the
// ~20-inst OCML polynomial without -ffast-math, which made the kernel
// VALU-bound (measured ~1440 VALU cyc/tile-wave vs ~250 expected).
// Row-sum via ones-MFMA; Opart partials normalized fp16 + l weight.
// ---------------------------------------------------------------------------
__global__ __launch_bounds__(512, 4) void flash_mfma(
    const _Float16* __restrict__ Q, long q_bs, long q_hs,
    const _Float16* __restrict__ K0, const _Float16* __restrict__ K1,
    long k_bs, long k_hs,
    const _Float16* __restrict__ VT0, const _Float16* __restrict__ VT1,
    long v_bs, long v_hs, int v_rs,
    _Float16* __restrict__ O,
    long o_bs, long o_hs, long o_rs, int o_cs,
    int nKtot, int nChunks, int kvMerge,
    _Float16* __restrict__ Opart, float* __restrict__ MLpart)
{
    __shared__ _Float16 Ks[2][64][72];
    __shared__ _Float16 VTs[2][64][72];
    const int t = threadIdx.x, lane = t & 63, L = lane & 15, quad = lane >> 4;
    const int wave = t >> 6;                       // 0..7
    // XCD-aware remap. Bijective over (x,y); requires gridDim.y==8, gx%8==0.
    const int h = blockIdx.x & 7;
    const int rest = (blockIdx.x >> 3) + (gridDim.x >> 3) * blockIdx.y;
    int b, which, nB;
    if (kvMerge) { b = blockIdx.z >> 1; which = blockIdx.z & 1; nB = gridDim.z >> 1; }
    else         { b = blockIdx.z;      which = 0;              nB = gridDim.z; }
    const int nMblk = gridDim.x / nChunks;
    const int mblk = rest / nChunks, chunk = rest % nChunks;
    const int m0 = mblk * 256;
    const int nkc = nKtot / nChunks, nbeg = chunk * nkc, nend = nbeg + nkc;

    const _Float16* K_ = (which ? K1 : K0) + (size_t)b * k_bs + (size_t)h * k_hs;
    const _Float16* V_ = (which ? VT1 : VT0) + (size_t)b * v_bs + (size_t)h * v_hs;

    // all-ones A-fragment for the row-sum MFMA (layout-independent)
    f16x8 onesA;
#pragma unroll
    for (int i = 0; i < 8; i++) onesA[i] = (_Float16)1.0f;

    // Q as B-fragments (each wave owns rows m0 + wave*32 + s*16 + L)
    f16x8 qf[2][2];
#pragma unroll
    for (int s = 0; s < 2; s++) {
        const size_t qrow = (size_t)b * q_bs + (size_t)h * q_hs
                          + (size_t)(m0 + wave * 32 + s * 16 + L) * 64;
        qf[s][0] = *(const f16x8*)&Q[qrow + quad * 8];
        qf[s][1] = *(const f16x8*)&Q[qrow + 32 + quad * 8];
    }

    f32x4 Oacc[2][4];
    f32x4 Lacc[2];
#pragma unroll
    for (int s = 0; s < 2; s++) {
#pragma unroll
        for (int i = 0; i < 4; i++) Oacc[s][i] = (f32x4){0.f, 0.f, 0.f, 0.f};
        Lacc[s] = (f32x4){0.f, 0.f, 0.f, 0.f};
    }

    // staging geometry: 512 threads cover [64][64] once: row t>>3, col (t&7)*8
    const int sr = t >> 3, sj = (t & 7) * 8;

    // prologue: stage tile nbeg into buffer 0
    {
        f16x8 a0 = *(const f16x8*)&K_[(size_t)(nbeg + sr) * 64 + sj];
        f16x8 a2 = *(const f16x8*)&V_[(size_t)sr * v_rs + nbeg + sj];
        *(f16x8*)&Ks[0][sr][sj]  = a0;
        *(f16x8*)&VTs[0][sr][sj] = a2;
    }
    __syncthreads();

    int cur = 0;
    for (int n0 = nbeg; n0 < nend; n0 += 64) {
        // issue next tile's global loads (latency hidden under compute)
        int nn = (n0 + 64 < nend) ? n0 + 64 : nbeg;
        f16x8 kp0 = *(const f16x8*)&K_[(size_t)(nn + sr) * 64 + sj];
        f16x8 vp0 = *(const f16x8*)&V_[(size_t)sr * v_rs + nn + sj];

        // QK^T (S^T layout) fused with softmax exp + fp16 pack.
        unsigned d0[2][4], d1[2][4];
#pragma unroll
        for (int c = 0; c < 4; c++) {
            f16x8 k0 = *(const f16x8*)&Ks[cur][c * 16 + L][quad * 8];
            f16x8 k1 = *(const f16x8*)&Ks[cur][c * 16 + L][32 + quad * 8];
#pragma unroll
            for (int s = 0; s < 2; s++) {
                f32x4 a = (f32x4){0.f, 0.f, 0.f, 0.f};
                a = __builtin_amdgcn_mfma_f32_16x16x32_f16(k0, qf[s][0], a, 0, 0, 0);
                a = __builtin_amdgcn_mfma_f32_16x16x32_f16(k1, qf[s][1], a, 0, 0, 0);
                float p0 = nexp2(a[0]);
                float p1 = nexp2(a[1]);
                float p2 = nexp2(a[2]);
                float p3 = nexp2(a[3]);
                d0[s][c] = pkh(p0, p1);
                d1[s][c] = pkh(p2, p3);
            }
        }

        // in-register P^T: build B-fragments pt[s][h2]
        f16x8 pt[2][2];
#pragma unroll
        for (int s = 0; s < 2; s++)
#pragma unroll
            for (int h2 = 0; h2 < 2; h2++) {
                unsigned a0 = d0[s][h2 * 2], b0 = d0[s][h2 * 2 + 1];
                swap32p(a0, b0); swap16p(a0, b0);
                unsigned a1 = d1[s][h2 * 2], b1 = d1[s][h2 * 2 + 1];
                swap32p(a1, b1); swap16p(a1, b1);
                union { unsigned u[4]; f16x8 v; } U;
                U.u[0] = a0; U.u[1] = a1; U.u[2] = b0; U.u[3] = b1;
                pt[s][h2] = U.v;
            }

#pragma unroll
        for (int h2 = 0; h2 < 2; h2++) {
#pragma unroll
            for (int dch = 0; dch < 4; dch++) {
                f16x8 vt = *(const f16x8*)&VTs[cur][dch * 16 + L][h2 * 32 + quad * 8];
                Oacc[0][dch] = __builtin_amdgcn_mfma_f32_16x16x32_f16(vt, pt[0][h2], Oacc[0][dch], 0, 0, 0);
                Oacc[1][dch] = __builtin_amdgcn_mfma_f32_16x16x32_f16(vt, pt[1][h2], Oacc[1][dch], 0, 0, 0);
            }
            // row-sum: D[*][m] = sum_k P^T[k][m]
            Lacc[0] = __builtin_amdgcn_mfma_f32_16x16x32_f16(onesA, pt[0][h2], Lacc[0], 0, 0, 0);
            Lacc[1] = __builtin_amdgcn_mfma_f32_16x16x32_f16(onesA, pt[1][h2], Lacc[1], 0, 0, 0);
        }

        // stage tile i+1 into the alternate buffer (WAR-safe: its readers
        // finished before the previous barrier)
        *(f16x8*)&Ks[cur ^ 1][sr][sj]  = kp0;
        *(f16x8*)&VTs[cur ^ 1][sr][sj] = vp0;
        __syncthreads();
        cur ^= 1;
    }

    // row-sums are complete per-lane (all D-rows equal; col = query L)
    float lt[2] = { Lacc[0][0], Lacc[1][0] };

    if (Opart) {
        int pid = (((which * nB + b) * gridDim.y + h) * nMblk + mblk) * nChunks + chunk;
        _Float16* Ob = Opart + (size_t)pid * (256 * 64);
        float* Mb = MLpart + (size_t)pid * 256;
#pragma unroll
        for (int s = 0; s < 2; s++) {
            int mloc = wave * 32 + s * 16 + L;
            float inv = 1.f / lt[s];
#pragma unroll
            for (int dch = 0; dch < 4; dch++) {
                union { _Float16 h[4]; uint2 u; } U;
#pragma unroll
                for (int r = 0; r < 4; r++)
                    U.h[r] = (_Float16)(Oacc[s][dch][r] * inv);
                *(uint2*)&Ob[mloc * 64 + dch * 16 + quad * 4] = U.u;
            }
            if (quad == 0) Mb[mloc] = lt[s];
        }
    } else {
#pragma unroll
        for (int s = 0; s < 2; s++) {
            float inv = 1.f / lt[s];
            size_t base = (size_t)b * o_bs + (size_t)h * o_hs
                        + (size_t)(m0 + wave * 32 + s * 16 + L) * o_rs;
#pragma unroll
            for (int dch = 0; dch < 4; dch++)
#pragma unroll
                for (int r = 0; r < 4; r++) {
                    int d = dch * 16 + quad * 4 + r;
                    O[base + (size_t)d * o_cs] = (_Float16)(Oacc[s][dch][r] * inv);
                }
        }
    }
}

// ---------------------------------------------------------------------------
// flash_combine: merge nChunks normalized fp16 partials, weighted by l.
// MERGED k+v: grid (M/4, H, 2*B); z < B -> O0 (kc), z >= B -> O1 (vc).
// Both outputs share layout [b][h][m][d] (o_bs, o_hs, row stride 64).
// Per-pid Opart 256x64 fp16, MLpart 256 floats (BM=256 partials).
// ---------------------------------------------------------------------------
__global__ __launch_bounds__(256) void flash_combine(
    const _Float16* __restrict__ Opart, const float* __restrict__ MLpart,
    int nMblk, int nChunks,
    _Float16* __restrict__ O0, _Float16* __restrict__ O1,
    long o_bs, long o_hs)
{
    const int t = threadIdx.x;
    const int zz = blockIdx.z, h = blockIdx.y;
    const int nB = gridDim.z >> 1;
    const int which = zz >= nB ? 1 : 0;
    const int b = which ? zz - nB : zz;
    _Float16* O = which ? O1 : O0;
    const int qm = blockIdx.x * 4 + (t >> 6), d = t & 63;
    const int mblk = qm >> 8, qloc = qm & 255;
    const int pb = (((which * nB + b) * gridDim.y + h) * nMblk + mblk) * nChunks;
    float num = 0.f, den = 0.f;
    for (int c = 0; c < nChunks; c++) {
        float lc = MLpart[(size_t)(pb + c) * 256 + qloc];
        num += lc * (float)Opart[(size_t)(pb + c) * 16384 + qloc * 64 + d];
        den += lc;
    }
    O[(size_t)b * o_bs + (size_t)h * o_hs + (size_t)qm * 64 + d] = (_Float16)(num / den);
}

// ---------------------------------------------------------------------------
extern "C" void kernel_launch(void* const* d_in, const int* in_sizes, int n_in,
                              void* d_out, int out_size, void* d_ws, size_t ws_size,
                              hipStream_t stream)
{
    const float* x      = (const float*)d_in[0];
    const float* w_qkv  = (const float*)d_in[1];
    const float* w_proj = (const float*)d_in[2];
    const float* b_proj = (const float*)d_in[3];
    const float* w_conv = (const float*)d_in[4];
    const float* b_conv = (const float*)d_in[5];
    const float* g_ln   = (const float*)d_in[6];
    const float* b_ln   = (const float*)d_in[7];
    const float* w_lin  = (const float*)d_in[8];
    const float* b_lin  = (const float*)d_in[9];
    float* out = (float*)d_out;
    (void)in_sizes; (void)n_in; (void)out_size; (void)ws_size;

    short* p = (short*)d_ws;
    size_t off = 0;
    auto alloc = [&](size_t n) { short* r = p + off; off += n; return r; };

    const size_t TN = (size_t)kB * kH * kN * kHD;   // 8.39M elems
    const size_t TM = (size_t)kB * kH * kM * kHD;   // 2.10M elems

    // region0: xf16, later ao (both fp16, lifetimes disjoint)
    _Float16* xf16 = (_Float16*)alloc((size_t)kB * kN * kC);
    _Float16* ao   = xf16;

    _Float16* wq16 = (_Float16*)alloc((size_t)kC3 * kC);
    _Float16* wp16 = (_Float16*)alloc((size_t)kC * kC);
    _Float16* qh  = (_Float16*)alloc(TN);
    _Float16* kh  = (_Float16*)alloc(TN);
    _Float16* vh  = (_Float16*)alloc(TN);
    _Float16* kT  = (_Float16*)alloc(TN);
    _Float16* vT  = (_Float16*)alloc(TN);
    _Float16* xsr = (_Float16*)alloc((size_t)kB * kM * kHD);
    _Float16* kc  = (_Float16*)alloc(TM);
    _Float16* vc  = (_Float16*)alloc(TM);   // [b,h,m,d] coalesced combine out
    _Float16* vcT = (_Float16*)alloc(TM);   // [b,h,d,m] for PV staging
    float*    MLpart = (float*)alloc((size_t)2048 * 128 * 2);
    _Float16* Opart  = (_Float16*)alloc((size_t)2048 * 8192);  // fp16 partials

    const int NCH = 4;   // compress key-chunks

    // 1. x -> fp16
    cvt_f16<<<(kB * kN * kC / 4 + 255) / 256, 256, 0, stream>>>(
        x, xf16, kB * kN * kC / 4);

    // 2. weights -> fp16 transposed
    wcvtT16<<<dim3(kC3 / 64, kC / 64), 256, 0, stream>>>(w_qkv, kC, kC3, wq16);
    wcvtT16<<<dim3(kC / 64, kC / 64), 256, 0, stream>>>(w_proj, kC, kC, wp16);

    // 3. qkv GEMM (fp16) -> q,k,v fp16 [b,h,n,d]; q pre-scaled by
    //    attn_scale*log2e = 0.125*1.4427
    gemm_f16<<<dim3(kC3 / 128, kB * kN / 128), 256, 0, stream>>>(
        xf16, wq16, kB * kN, kC3, kC, 1, 0.18033688f, nullptr, nullptr,
        qh, kh, vh);

    // 4. k,v -> kT,vT ([b,h,d,n])
    transpose_hd<<<dim3(kN / 64, kB * kH, 2), 256, 0, stream>>>(
        (const short*)kh, (const short*)vh, (short*)kT, (short*)vT, kN);

    // 5. SR branch -> xsr fp16 (pre-scaled by log2e)
    sr_fused<<<dim3(kM, kB), 256, 0, stream>>>(
        x, w_conv, b_conv, g_ln, b_ln, w_lin, b_lin, xsr);

    // 6. merged compress k+v (4 chunks each); BM=256, 512-thread blocks
    flash_mfma<<<dim3(4 * NCH, kH, kB * 2), 512, 0, stream>>>(
        xsr, (long)kM * kHD, 0L,
        kh, vh, (long)kH * kN * kHD, (long)kN * kHD,
        kT, vT, (long)kH * kHD * kN, (long)kHD * kN, kN,
        nullptr, 0L, 0L, 0L, 0,
        kN, NCH, 1, Opart, MLpart);
    // merged combine: z<B -> kc, z>=B -> vc (both [b,h,m,d])
    flash_combine<<<dim3(kM / 4, kH, kB * 2), 256, 0, stream>>>(
        Opart, MLpart, 4, NCH,
        kc, vc, (long)kH * kM * kHD, (long)kM * kHD);
    transpose_hd<<<dim3(kM / 64, kB * kH, 1), 256, 0, stream>>>(
        (const short*)vc, (const short*)vc, (short*)vcT, (short*)vcT, kM);

    // 7. main attention -> ao fp16 [b][n][h*64+d]; BM=256, 512-thread blocks
    flash_mfma<<<dim3(16, kH, kB), 512, 0, stream>>>(
        qh, (long)kH * kN * kHD, (long)kN * kHD,
        kc, kc, (long)kH * kM * kHD, (long)kM * kHD,
        vcT, vcT, (long)kH * kHD * kM, (long)kHD * kM, kM,
        ao, (long)kN * kC, 64L, (long)kC, 1,
        kM, 1, 0, nullptr, nullptr);

    // 8. proj GEMM (fp16) -> out fp32 (+bias)
    gemm_f16<<<dim3(kC / 128, kB * kN / 128), 256, 0, stream>>>(
        ao, wp16, kB * kN, kC, kC, 0, 1.0f, b_proj, out,
        nullptr, nullptr, nullptr);
}

// Round 13
// 352.448 us; speedup vs baseline: 1.3170x; 1.0039x over previous
//
#include <hip/hip_runtime.h>

typedef float f32x4 __attribute__((ext_vector_type(4)));
typedef short bf16x8 __attribute__((ext_vector_type(8)));
typedef _Float16 f16x8 __attribute__((ext_vector_type(8)));
typedef __fp16 fp16x2 __attribute__((ext_vector_type(2)));

constexpr int kB  = 4;
constexpr int kN  = 4096;
constexpr int kC  = 512;
constexpr int kH  = 8;
constexpr int kHD = 64;
constexpr int kM  = 1024;
constexpr int kC3 = 1536;

// native hardware exp2: ONE v_exp_f32 (quarter-rate) instead of the OCML
// polynomial (~20 VALU insts) that plain exp2f() lowers to w/o -ffast-math.
__device__ inline float nexp2(float x) {
#if __has_builtin(__builtin_amdgcn_exp2f)
    return __builtin_amdgcn_exp2f(x);
#else
    float r;
    asm("v_exp_f32 %0, %1" : "=v"(r) : "v"(x));
    return r;
#endif
}

// pack 2 floats -> 2 fp16 in one dword (v_cvt_pkrtz_f16_f32, 1 inst)
__device__ inline unsigned pkh(float a, float b) {
    union { fp16x2 h; unsigned u; } u;
    u.h = __builtin_amdgcn_cvt_pkrtz(a, b);
    return u.u;
}

// permlane swaps: exchange quad-rows between two regs (gfx950).
__device__ inline void swap32p(unsigned &a, unsigned &b) {
#if __has_builtin(__builtin_amdgcn_permlane32_swap)
    auto r = __builtin_amdgcn_permlane32_swap(a, b, false, false);
    a = r[0]; b = r[1];
#else
    asm volatile("v_permlane32_swap_b32 %0, %1" : "+v"(a), "+v"(b));
#endif
}
__device__ inline void swap16p(unsigned &a, unsigned &b) {
#if __has_builtin(__builtin_amdgcn_permlane16_swap)
    auto r = __builtin_amdgcn_permlane16_swap(a, b, false, false);
    a = r[0]; b = r[1];
#else
    asm volatile("v_permlane16_swap_b32 %0, %1" : "+v"(a), "+v"(b));
#endif
}

// async global->LDS, 16B per lane. LDS dest = uniform base + lane*16.
__device__ inline void gl_lds16(const _Float16* g, _Float16* l) {
    __builtin_amdgcn_global_load_lds(
        (const __attribute__((address_space(1))) unsigned int*)(const void*)g,
        (__attribute__((address_space(3))) unsigned int*)(void*)l, 16, 0, 0);
}

// ---------------------------------------------------------------------------
// cvt_f16: fp32 -> fp16 flat. n4 = count/4.
// ---------------------------------------------------------------------------
__global__ __launch_bounds__(256) void cvt_f16(
    const float* __restrict__ X, _Float16* __restrict__ Y, int n4)
{
    int i = blockIdx.x * 256 + threadIdx.x;
    if (i >= n4) return;
    float4 v = ((const float4*)X)[i];
    union { _Float16 h[4]; short4 s; } u;
    u.h[0] = (_Float16)v.x; u.h[1] = (_Float16)v.y;
    u.h[2] = (_Float16)v.z; u.h[3] = (_Float16)v.w;
    ((short4*)Y)[i] = u.s;
}

// ---------------------------------------------------------------------------
// wcvtT16: W [K][N] fp32 -> T [N][K] fp16 (transposed)
// ---------------------------------------------------------------------------
__global__ __launch_bounds__(256) void wcvtT16(
    const float* __restrict__ W, int K, int N, _Float16* __restrict__ T16)
{
    __shared__ float T[64][65];
    const int n0 = blockIdx.x * 64, k0 = blockIdx.y * 64;
    const int t = threadIdx.x;
#pragma unroll
    for (int i = 0; i < 4; i++) {
        int c = t + i * 256;
        int row = c >> 4, col4 = (c & 15) * 4;
        *(float4*)&T[row][col4] = *(const float4*)&W[(size_t)(k0 + row) * N + n0 + col4];
    }
    __syncthreads();
#pragma unroll
    for (int i = 0; i < 4; i++) {
        int c = t + i * 256;
        int nrow = c >> 4, kc4 = (c & 15) * 4;
        union { _Float16 h[4]; short4 s; } u;
        u.h[0] = (_Float16)T[kc4 + 0][nrow];
        u.h[1] = (_Float16)T[kc4 + 1][nrow];
        u.h[2] = (_Float16)T[kc4 + 2][nrow];
        u.h[3] = (_Float16)T[kc4 + 3][nrow];
        *(short4*)&T16[(size_t)(n0 + nrow) * K + k0 + kc4] = u.s;
    }
}

// ---------------------------------------------------------------------------
// transpose_hd: [bh][nTok][64] -> [bh][64][nTok], 2 arrays (bit-agnostic 16b).
// ---------------------------------------------------------------------------
__global__ __launch_bounds__(256) void transpose_hd(
    const short* __restrict__ s0, const short* __restrict__ s1,
    short* __restrict__ d0, short* __restrict__ d1, int nTok)
{
    __shared__ short T[64][72];
    const short* src = blockIdx.z == 0 ? s0 : s1;
    short*       dst = blockIdx.z == 0 ? d0 : d1;
    const int n0 = blockIdx.x * 64, bh = blockIdx.y;
    const int t = threadIdx.x;
#pragma unroll
    for (int i = 0; i < 2; i++) {
        int c = t + i * 256;
        int row = c >> 3, j = (c & 7) * 8;
        *(bf16x8*)&T[row][j] = *(const bf16x8*)&src[((size_t)bh * nTok + n0 + row) * 64 + j];
    }
    __syncthreads();
#pragma unroll
    for (int i = 0; i < 2; i++) {
        int c = t + i * 256;
        int drow = c >> 3, j = (c & 7) * 8;
        bf16x8 v;
#pragma unroll
        for (int q = 0; q < 8; q++) v[q] = T[j + q][drow];
        *(bf16x8*)&dst[((size_t)bh * 64 + drow) * nTok + n0 + j] = v;
    }
}

// ---------------------------------------------------------------------------
// gemm_f16: C[Md,Nd] = A[Md,Kd] @ B^T[Nd,Kd], fp16 in, fp32 accumulate.
// mode 0: Cf[row][col] = acc + bias (fp32). mode 1: qkv scatter to fp16 via
// LDS-BOUNCE epilogue: acc packed into a [128][72] fp16 tile (reusing the
// dead Ash/Bsh space), then 16B dwordx4 stores — 16x fewer VMEM stores and
// 128B-contiguous rows vs the old 64 scalar 2B stores/thread.
// 128x128 tile, BK=32, 4 waves; staging via async global_load_lds width=16.
// ---------------------------------------------------------------------------
__global__ __launch_bounds__(256) void gemm_f16(
    const _Float16* __restrict__ A, const _Float16* __restrict__ B,
    int Md, int Nd, int Kd, int mode, float qscale,
    const float* __restrict__ bias, float* __restrict__ Cf,
    _Float16* __restrict__ q, _Float16* __restrict__ k, _Float16* __restrict__ v)
{
    __shared__ _Float16 SH[9216];                      // 18,432 B union
    _Float16 (*Ash)[32] = (_Float16 (*)[32])SH;        // [128][32]
    _Float16 (*Bsh)[32] = (_Float16 (*)[32])&SH[4096]; // [128][32]
    const int t = threadIdx.x, lane = t & 63, L = lane & 15, quad = lane >> 4;
    const int wave = t >> 6, wm = wave >> 1, wn = wave & 1;
    const int bm = blockIdx.y * 128, bn = blockIdx.x * 128;
    const int r16 = lane >> 2, c16 = lane & 3;   // staging: row-in-chunk, col16

    f32x4 acc[4][4];
#pragma unroll
    for (int i = 0; i < 4; i++)
#pragma unroll
        for (int j = 0; j < 4; j++) acc[i][j] = (f32x4){0.f, 0.f, 0.f, 0.f};

    for (int k0 = 0; k0 < Kd; k0 += 32) {
#pragma unroll
        for (int i = 0; i < 2; i++) {
            int chunk = wave * 2 + i;          // 8 chunks of 16 rows
            int row = chunk * 16 + r16;
            gl_lds16(&A[(size_t)(bm + row) * Kd + k0 + c16 * 8], &Ash[chunk * 16][0]);
            gl_lds16(&B[(size_t)(bn + row) * Kd + k0 + c16 * 8], &Bsh[chunk * 16][0]);
        }
        __syncthreads();
        f16x8 af[4];
#pragma unroll
        for (int mi = 0; mi < 4; mi++)
            af[mi] = *(const f16x8*)&Ash[wm * 64 + mi * 16 + L][quad * 8];
#pragma unroll
        for (int ni = 0; ni < 4; ni++) {
            f16x8 bf = *(const f16x8*)&Bsh[wn * 64 + ni * 16 + L][quad * 8];
#pragma unroll
            for (int mi = 0; mi < 4; mi++)
                acc[mi][ni] = __builtin_amdgcn_mfma_f32_16x16x32_f16(af[mi], bf, acc[mi][ni], 0, 0, 0);
        }
        __syncthreads();
    }

    if (mode == 0) {
#pragma unroll
        for (int ni = 0; ni < 4; ni++) {
            int col = bn + wn * 64 + ni * 16 + L;
            float bb = bias ? bias[col] : 0.f;
#pragma unroll
            for (int mi = 0; mi < 4; mi++)
#pragma unroll
                for (int r = 0; r < 4; r++) {
                    int row = bm + wm * 64 + mi * 16 + quad * 4 + r;
                    Cf[(size_t)row * Nd + col] = acc[mi][ni][r] + bb;
                }
        }
    } else {
        // LDS-bounce epilogue, one 64-col half at a time (half = one (s,h)).
        _Float16 (*Bnc)[72] = (_Float16 (*)[72])SH;   // Ash/Bsh dead now
#pragma unroll
        for (int half = 0; half < 2; half++) {
            int colb = bn + half * 64;               // 64-aligned
            int s = colb >> 9, h = (colb >> 6) & 7;
            float sc = (s == 0) ? qscale : 1.0f;
            if (wn == half) {
#pragma unroll
                for (int ni = 0; ni < 4; ni++)
#pragma unroll
                    for (int mi = 0; mi < 4; mi++)
#pragma unroll
                        for (int r = 0; r < 4; r++)
                            Bnc[wm * 64 + mi * 16 + quad * 4 + r][ni * 16 + L] =
                                (_Float16)(acc[mi][ni][r] * sc);
            }
            __syncthreads();
            _Float16* dst = s == 0 ? q : s == 1 ? k : v;
            int row = t >> 1, cg = (t & 1) * 32;
            int brow = bm + row, bb = brow >> 12, n = brow & 4095;
            _Float16* base = dst + (((size_t)bb * 8 + h) * 4096 + n) * 64;
#pragma unroll
            for (int i = 0; i < 4; i++)
                *(f16x8*)&base[cg + i * 8] = *(const f16x8*)&Bnc[row][cg + i * 8];
            __syncthreads();
        }
    }
}

// ---------------------------------------------------------------------------
// sr_fused: depthwise 2x2/s2 conv + LayerNorm + linear -> xsr fp16.
// Output pre-scaled by log2e (softmax scale fold, f32-side, rounding-neutral).
// ---------------------------------------------------------------------------
__global__ __launch_bounds__(256) void sr_fused(
    const float* __restrict__ x, const float* __restrict__ wconv,
    const float* __restrict__ bconv, const float* __restrict__ gamma,
    const float* __restrict__ beta, const float* __restrict__ wlin,
    const float* __restrict__ blin, _Float16* __restrict__ xsr)
{
    __shared__ float nbuf[512];
    __shared__ float red[8];
    __shared__ float stats[2];
    __shared__ float pbuf[4][64];

    const int m = blockIdx.x, b = blockIdx.y;
    const int oy = m >> 5, ox = m & 31;
    const int t = threadIdx.x;
    const float* xb = x + (size_t)b * kN * kC;

    float vals[2], s = 0.f, sq = 0.f;
#pragma unroll
    for (int i = 0; i < 2; i++) {
        int c = t + i * 256;
        float acc = bconv[c];
#pragma unroll
        for (int dy = 0; dy < 2; dy++)
#pragma unroll
            for (int dx = 0; dx < 2; dx++) {
                int n = (oy * 2 + dy) * 64 + (ox * 2 + dx);
                acc += xb[(size_t)n * kC + c] * wconv[c * 4 + dy * 2 + dx];
            }
        vals[i] = acc;
        s += acc; sq += acc * acc;
    }
#pragma unroll
    for (int off = 32; off > 0; off >>= 1) {
        s  += __shfl_down(s,  off);
        sq += __shfl_down(sq, off);
    }
    if ((t & 63) == 0) { red[t >> 6] = s; red[4 + (t >> 6)] = sq; }
    __syncthreads();
    if (t == 0) {
        float ts = red[0] + red[1] + red[2] + red[3];
        float tq = red[4] + red[5] + red[6] + red[7];
        float mean = ts * (1.f / 512.f);
        float var  = tq * (1.f / 512.f) - mean * mean;
        stats[0] = mean;
        stats[1] = rsqrtf(var + 1e-5f);
    }
    __syncthreads();
    const float mean = stats[0], rstd = stats[1];
#pragma unroll
    for (int i = 0; i < 2; i++) {
        int c = t + i * 256;
        nbuf[c] = (vals[i] - mean) * rstd * gamma[c] + beta[c];
    }
    __syncthreads();
    const int d = t & 63, part = t >> 6;
    float p = 0.f;
    for (int c = part * 128; c < (part + 1) * 128; c++)
        p += nbuf[c] * wlin[c * 64 + d];
    pbuf[part][d] = p;
    __syncthreads();
    if (t < 64) {
        float o = pbuf[0][t] + pbuf[1][t] + pbuf[2][t] + pbuf[3][t] + blin[t];
        xsr[((size_t)b * kM + m) * kHD + t] = (_Float16)(o * 1.44269504089f);
    }
}

// ---------------------------------------------------------------------------
// MFMA flash attention, fp16, transposed-S, in-register P^T via permlane
// swaps, double-buffered LDS, ONE barrier per tile, XCD-aware work remap.
// BM=256, 8 waves / 512 threads, launch_bounds(512,4).
// p = nexp2(a): native v_exp_f32. QK C-in uses a hoisted kZero register
// quartet (no per-iteration zero-init movs on the saturated VALU).
// Row-sum via ones-MFMA; Opart partials normalized fp16 + l weight.
// ---------------------------------------------------------------------------
__global__ __launch_bounds__(512, 4) void flash_mfma(
    const _Float16* __restrict__ Q, long q_bs, long q_hs,
    const _Float16* __restrict__ K0, const _Float16* __restrict__ K1,
    long k_bs, long k_hs,
    const _Float16* __restrict__ VT0, const _Float16* __restrict__ VT1,
    long v_bs, long v_hs, int v_rs,
    _Float16* __restrict__ O,
    long o_bs, long o_hs, long o_rs, int o_cs,
    int nKtot, int nChunks, int kvMerge,
    _Float16* __restrict__ Opart, float* __restrict__ MLpart)
{
    __shared__ _Float16 Ks[2][64][72];
    __shared__ _Float16 VTs[2][64][72];
    const int t = threadIdx.x, lane = t & 63, L = lane & 15, quad = lane >> 4;
    const int wave = t >> 6;                       // 0..7
    // XCD-aware remap. Bijective over (x,y); requires gridDim.y==8, gx%8==0.
    const int h = blockIdx.x & 7;
    const int rest = (blockIdx.x >> 3) + (gridDim.x >> 3) * blockIdx.y;
    int b, which, nB;
    if (kvMerge) { b = blockIdx.z >> 1; which = blockIdx.z & 1; nB = gridDim.z >> 1; }
    else         { b = blockIdx.z;      which = 0;              nB = gridDim.z; }
    const int nMblk = gridDim.x / nChunks;
    const int mblk = rest / nChunks, chunk = rest % nChunks;
    const int m0 = mblk * 256;
    const int nkc = nKtot / nChunks, nbeg = chunk * nkc, nend = nbeg + nkc;

    const _Float16* K_ = (which ? K1 : K0) + (size_t)b * k_bs + (size_t)h * k_hs;
    const _Float16* V_ = (which ? VT1 : VT0) + (size_t)b * v_bs + (size_t)h * v_hs;

    // all-ones A-fragment for the row-sum MFMA (layout-independent)
    f16x8 onesA;
#pragma unroll
    for (int i = 0; i < 8; i++) onesA[i] = (_Float16)1.0f;

    // Q as B-fragments (each wave owns rows m0 + wave*32 + s*16 + L)
    f16x8 qf[2][2];
#pragma unroll
    for (int s = 0; s < 2; s++) {
        const size_t qrow = (size_t)b * q_bs + (size_t)h * q_hs
                          + (size_t)(m0 + wave * 32 + s * 16 + L) * 64;
        qf[s][0] = *(const f16x8*)&Q[qrow + quad * 8];
        qf[s][1] = *(const f16x8*)&Q[qrow + 32 + quad * 8];
    }

    f32x4 Oacc[2][4];
    f32x4 Lacc[2];
#pragma unroll
    for (int s = 0; s < 2; s++) {
#pragma unroll
        for (int i = 0; i < 4; i++) Oacc[s][i] = (f32x4){0.f, 0.f, 0.f, 0.f};
        Lacc[s] = (f32x4){0.f, 0.f, 0.f, 0.f};
    }
    const f32x4 kZero = (f32x4){0.f, 0.f, 0.f, 0.f};   // hoisted QK C-in

    // staging geometry: 512 threads cover [64][64] once: row t>>3, col (t&7)*8
    const int sr = t >> 3, sj = (t & 7) * 8;

    // prologue: stage tile nbeg into buffer 0
    {
        f16x8 a0 = *(const f16x8*)&K_[(size_t)(nbeg + sr) * 64 + sj];
        f16x8 a2 = *(const f16x8*)&V_[(size_t)sr * v_rs + nbeg + sj];
        *(f16x8*)&Ks[0][sr][sj]  = a0;
        *(f16x8*)&VTs[0][sr][sj] = a2;
    }
    __syncthreads();

    int cur = 0;
    for (int n0 = nbeg; n0 < nend; n0 += 64) {
        // issue next tile's global loads (latency hidden under compute)
        int nn = (n0 + 64 < nend) ? n0 + 64 : nbeg;
        f16x8 kp0 = *(const f16x8*)&K_[(size_t)(nn + sr) * 64 + sj];
        f16x8 vp0 = *(const f16x8*)&V_[(size_t)sr * v_rs + nn + sj];

        // QK^T (S^T layout) fused with softmax exp + fp16 pack.
        unsigned d0[2][4], d1[2][4];
#pragma unroll
        for (int c = 0; c < 4; c++) {
            f16x8 k0 = *(const f16x8*)&Ks[cur][c * 16 + L][quad * 8];
            f16x8 k1 = *(const f16x8*)&Ks[cur][c * 16 + L][32 + quad * 8];
#pragma unroll
            for (int s = 0; s < 2; s++) {
                f32x4 a = __builtin_amdgcn_mfma_f32_16x16x32_f16(k0, qf[s][0], kZero, 0, 0, 0);
                a = __builtin_amdgcn_mfma_f32_16x16x32_f16(k1, qf[s][1], a, 0, 0, 0);
                float p0 = nexp2(a[0]);
                float p1 = nexp2(a[1]);
                float p2 = nexp2(a[2]);
                float p3 = nexp2(a[3]);
                d0[s][c] = pkh(p0, p1);
                d1[s][c] = pkh(p2, p3);
            }
        }

        // in-register P^T: build B-fragments pt[s][h2]
        f16x8 pt[2][2];
#pragma unroll
        for (int s = 0; s < 2; s++)
#pragma unroll
            for (int h2 = 0; h2 < 2; h2++) {
                unsigned a0 = d0[s][h2 * 2], b0 = d0[s][h2 * 2 + 1];
                swap32p(a0, b0); swap16p(a0, b0);
                unsigned a1 = d1[s][h2 * 2], b1 = d1[s][h2 * 2 + 1];
                swap32p(a1, b1); swap16p(a1, b1);
                union { unsigned u[4]; f16x8 v; } U;
                U.u[0] = a0; U.u[1] = a1; U.u[2] = b0; U.u[3] = b1;
                pt[s][h2] = U.v;
            }

#pragma unroll
        for (int h2 = 0; h2 < 2; h2++) {
#pragma unroll
            for (int dch = 0; dch < 4; dch++) {
                f16x8 vt = *(const f16x8*)&VTs[cur][dch * 16 + L][h2 * 32 + quad * 8];
                Oacc[0][dch] = __builtin_amdgcn_mfma_f32_16x16x32_f16(vt, pt[0][h2], Oacc[0][dch], 0, 0, 0);
                Oacc[1][dch] = __builtin_amdgcn_mfma_f32_16x16x32_f16(vt, pt[1][h2], Oacc[1][dch], 0, 0, 0);
            }
            // row-sum: D[*][m] = sum_k P^T[k][m]
            Lacc[0] = __builtin_amdgcn_mfma_f32_16x16x32_f16(onesA, pt[0][h2], Lacc[0], 0, 0, 0);
            Lacc[1] = __builtin_amdgcn_mfma_f32_16x16x32_f16(onesA, pt[1][h2], Lacc[1], 0, 0, 0);
        }

        // stage tile i+1 into the alternate buffer (WAR-safe: its readers
        // finished before the previous barrier)
        *(f16x8*)&Ks[cur ^ 1][sr][sj]  = kp0;
        *(f16x8*)&VTs[cur ^ 1][sr][sj] = vp0;
        __syncthreads();
        cur ^= 1;
    }

    // row-sums are complete per-lane (all D-rows equal; col = query L)
    float lt[2] = { Lacc[0][0], Lacc[1][0] };

    if (Opart) {
        int pid = (((which * nB + b) * gridDim.y + h) * nMblk + mblk) * nChunks + chunk;
        _Float16* Ob = Opart + (size_t)pid * (256 * 64);
        float* Mb = MLpart + (size_t)pid * 256;
#pragma unroll
        for (int s = 0; s < 2; s++) {
            int mloc = wave * 32 + s * 16 + L;
            float inv = 1.f / lt[s];
#pragma unroll
            for (int dch = 0; dch < 4; dch++) {
                union { _Float16 h[4]; uint2 u; } U;
#pragma unroll
                for (int r = 0; r < 4; r++)
                    U.h[r] = (_Float16)(Oacc[s][dch][r] * inv);
                *(uint2*)&Ob[mloc * 64 + dch * 16 + quad * 4] = U.u;
            }
            if (quad == 0) Mb[mloc] = lt[s];
        }
    } else {
#pragma unroll
        for (int s = 0; s < 2; s++) {
            float inv = 1.f / lt[s];
            size_t base = (size_t)b * o_bs + (size_t)h * o_hs
                        + (size_t)(m0 + wave * 32 + s * 16 + L) * o_rs;
#pragma unroll
            for (int dch = 0; dch < 4; dch++)
#pragma unroll
                for (int r = 0; r < 4; r++) {
                    int d = dch * 16 + quad * 4 + r;
                    O[base + (size_t)d * o_cs] = (_Float16)(Oacc[s][dch][r] * inv);
                }
        }
    }
}

// ---------------------------------------------------------------------------
// flash_combine: merge nChunks normalized fp16 partials, weighted by l.
// MERGED k+v: grid (M/4, H, 2*B); z < B -> O0 (kc), z >= B -> O1 (vc).
// Both outputs share layout [b][h][m][d] (o_bs, o_hs, row stride 64).
// Per-pid Opart 256x64 fp16, MLpart 256 floats (BM=256 partials).
// ---------------------------------------------------------------------------
__global__ __launch_bounds__(256) void flash_combine(
    const _Float16* __restrict__ Opart, const float* __restrict__ MLpart,
    int nMblk, int nChunks,
    _Float16* __restrict__ O0, _Float16* __restrict__ O1,
    long o_bs, long o_hs)
{
    const int t = threadIdx.x;
    const int zz = blockIdx.z, h = blockIdx.y;
    const int nB = gridDim.z >> 1;
    const int which = zz >= nB ? 1 : 0;
    const int b = which ? zz - nB : zz;
    _Float16* O = which ? O1 : O0;
    const int qm = blockIdx.x * 4 + (t >> 6), d = t & 63;
    const int mblk = qm >> 8, qloc = qm & 255;
    const int pb = (((which * nB + b) * gridDim.y + h) * nMblk + mblk) * nChunks;
    float num = 0.f, den = 0.f;
    for (int c = 0; c < nChunks; c++) {
        float lc = MLpart[(size_t)(pb + c) * 256 + qloc];
        num += lc * (float)Opart[(size_t)(pb + c) * 16384 + qloc * 64 + d];
        den += lc;
    }
    O[(size_t)b * o_bs + (size_t)h * o_hs + (size_t)qm * 64 + d] = (_Float16)(num / den);
}

// ---------------------------------------------------------------------------
extern "C" void kernel_launch(void* const* d_in, const int* in_sizes, int n_in,
                              void* d_out, int out_size, void* d_ws, size_t ws_size,
                              hipStream_t stream)
{
    const float* x      = (const float*)d_in[0];
    const float* w_qkv  = (const float*)d_in[1];
    const float* w_proj = (const float*)d_in[2];
    const float* b_proj = (const float*)d_in[3];
    const float* w_conv = (const float*)d_in[4];
    const float* b_conv = (const float*)d_in[5];
    const float* g_ln   = (const float*)d_in[6];
    const float* b_ln   = (const float*)d_in[7];
    const float* w_lin  = (const float*)d_in[8];
    const float* b_lin  = (const float*)d_in[9];
    float* out = (float*)d_out;
    (void)in_sizes; (void)n_in; (void)out_size; (void)ws_size;

    short* p = (short*)d_ws;
    size_t off = 0;
    auto alloc = [&](size_t n) { short* r = p + off; off += n; return r; };

    const size_t TN = (size_t)kB * kH * kN * kHD;   // 8.39M elems
    const size_t TM = (size_t)kB * kH * kM * kHD;   // 2.10M elems

    // region0: xf16, later ao (both fp16, lifetimes disjoint)
    _Float16* xf16 = (_Float16*)alloc((size_t)kB * kN * kC);
    _Float16* ao   = xf16;

    _Float16* wq16 = (_Float16*)alloc((size_t)kC3 * kC);
    _Float16* wp16 = (_Float16*)alloc((size_t)kC * kC);
    _Float16* qh  = (_Float16*)alloc(TN);
    _Float16* kh  = (_Float16*)alloc(TN);
    _Float16* vh  = (_Float16*)alloc(TN);
    _Float16* kT  = (_Float16*)alloc(TN);
    _Float16* vT  = (_Float16*)alloc(TN);
    _Float16* xsr = (_Float16*)alloc((size_t)kB * kM * kHD);
    _Float16* kc  = (_Float16*)alloc(TM);
    _Float16* vc  = (_Float16*)alloc(TM);   // [b,h,m,d] coalesced combine out
    _Float16* vcT = (_Float16*)alloc(TM);   // [b,h,d,m] for PV staging
    float*    MLpart = (float*)alloc((size_t)2048 * 128 * 2);
    _Float16* Opart  = (_Float16*)alloc((size_t)2048 * 8192);  // fp16 partials

    const int NCH = 4;   // compress key-chunks

    // 1. x -> fp16
    cvt_f16<<<(kB * kN * kC / 4 + 255) / 256, 256, 0, stream>>>(
        x, xf16, kB * kN * kC / 4);

    // 2. weights -> fp16 transposed
    wcvtT16<<<dim3(kC3 / 64, kC / 64), 256, 0, stream>>>(w_qkv, kC, kC3, wq16);
    wcvtT16<<<dim3(kC / 64, kC / 64), 256, 0, stream>>>(w_proj, kC, kC, wp16);

    // 3. qkv GEMM (fp16) -> q,k,v fp16 [b,h,n,d]; q pre-scaled by
    //    attn_scale*log2e = 0.125*1.4427
    gemm_f16<<<dim3(kC3 / 128, kB * kN / 128), 256, 0, stream>>>(
        xf16, wq16, kB * kN, kC3, kC, 1, 0.18033688f, nullptr, nullptr,
        qh, kh, vh);

    // 4. k,v -> kT,vT ([b,h,d,n])
    transpose_hd<<<dim3(kN / 64, kB * kH, 2), 256, 0, stream>>>(
        (const short*)kh, (const short*)vh, (short*)kT, (short*)vT, kN);

    // 5. SR branch -> xsr fp16 (pre-scaled by log2e)
    sr_fused<<<dim3(kM, kB), 256, 0, stream>>>(
        x, w_conv, b_conv, g_ln, b_ln, w_lin, b_lin, xsr);

    // 6. merged compress k+v (4 chunks each); BM=256, 512-thread blocks
    flash_mfma<<<dim3(4 * NCH, kH, kB * 2), 512, 0, stream>>>(
        xsr, (long)kM * kHD, 0L,
        kh, vh, (long)kH * kN * kHD, (long)kN * kHD,
        kT, vT, (long)kH * kHD * kN, (long)kHD * kN, kN,
        nullptr, 0L, 0L, 0L, 0,
        kN, NCH, 1, Opart, MLpart);
    // merged combine: z<B -> kc, z>=B -> vc (both [b,h,m,d])
    flash_combine<<<dim3(kM / 4, kH, kB * 2), 256, 0, stream>>>(
        Opart, MLpart, 4, NCH,
        kc, vc, (long)kH * kM * kHD, (long)kM * kHD);
    transpose_hd<<<dim3(kM / 64, kB * kH, 1), 256, 0, stream>>>(
        (const short*)vc, (const short*)vc, (short*)vcT, (short*)vcT, kM);

    // 7. main attention -> ao fp16 [b][n][h*64+d]; BM=256, 512-thread blocks
    flash_mfma<<<dim3(16, kH, kB), 512, 0, stream>>>(
        qh, (long)kH * kN * kHD, (long)kN * kHD,
        kc, kc, (long)kH * kM * kHD, (long)kM * kHD,
        vcT, vcT, (long)kH * kHD * kM, (long)kHD * kM, kM,
        ao, (long)kN * kC, 64L, (long)kC, 1,
        kM, 1, 0, nullptr, nullptr);

    // 8. proj GEMM (fp16) -> out fp32 (+bias)
    gemm_f16<<<dim3(kC / 128, kB * kN / 128), 256, 0, stream>>>(
        ao, wp16, kB * kN, kC, kC, 0, 1.0f, b_proj, out,
        nullptr, nullptr, nullptr);
}